// Round 10
// baseline (547.843 us; speedup 1.0000x reference)
//
#include <hip/hip_runtime.h>
#include <hip/hip_bf16.h>
#include <math.h>

#define N_NODES 50000
#define N_EDGES 800000
#define EMB 128
#define LH 256
#define NSENT 2048
#define MAXLEN 32
#define SCAN_NB 196   // ceil(50000/256)
#define NG 64         // sentences per group
#define NGRP 32       // groups (NSENT/NG)

typedef __attribute__((ext_vector_type(8))) short short8;
typedef __attribute__((ext_vector_type(4))) float f32x4;

__device__ __forceinline__ unsigned short f2bf_u(float f) {
    __hip_bfloat16 h = __float2bfloat16(f);
    return *reinterpret_cast<unsigned short*>(&h);
}
__device__ __forceinline__ float bfu2f(unsigned short u) {
    unsigned int x = ((unsigned int)u) << 16;
    return __uint_as_float(x);
}

// fast activations: ~1e-7 abs error, negligible vs bf16 h-state rounding (2^-9)
__device__ __forceinline__ float fsig(float x) {
    return 1.f / (1.f + __expf(-x));
}
__device__ __forceinline__ float ftanh(float x) {
    return 1.f - 2.f / (__expf(2.f * x) + 1.f);
}

#define WAITVM0() __builtin_amdgcn_s_waitcnt(0xF70)   // vmcnt(0)

// async global->LDS, 16B/lane; gsrc per-lane, LDS dst = wave-uniform base + lane*16
__device__ __forceinline__ void gload_lds16(const void* gsrc, void* ldst) {
    __builtin_amdgcn_global_load_lds(
        (const __attribute__((address_space(1))) unsigned int*)gsrc,
        (__attribute__((address_space(3))) unsigned int*)ldst, 16, 0, 0);
}

// ---------------- CSR build ----------------

__global__ void k_hist(const int* __restrict__ dst, int* __restrict__ cnt) {
    int i = blockIdx.x * 256 + threadIdx.x;
    if (i < N_EDGES) atomicAdd(&cnt[dst[i]], 1);
}

__global__ void k_scan_blk(const int* __restrict__ cnt, int* __restrict__ row_ptr,
                           int* __restrict__ blk) {
    int b = blockIdx.x, t = threadIdx.x;
    int i = b * 256 + t;
    int lane = t & 63, wid = t >> 6;
    int v = (i < N_NODES) ? cnt[i] : 0;
    int x = v;
    #pragma unroll
    for (int off = 1; off < 64; off <<= 1) {
        int y = __shfl_up(x, off);
        if (lane >= off) x += y;
    }
    __shared__ int ws[4];
    if (lane == 63) ws[wid] = x;
    __syncthreads();
    if (t == 0) {
        int s = 0;
        #pragma unroll
        for (int j = 0; j < 4; j++) { int tmp = ws[j]; ws[j] = s; s += tmp; }
        blk[b] = s;
    }
    __syncthreads();
    if (i < N_NODES) row_ptr[i] = ws[wid] + x - v;
}

__global__ void k_scan_tot(int* __restrict__ blk) {
    int t = threadIdx.x;
    int lane = t & 63, wid = t >> 6;
    int v = (t < SCAN_NB) ? blk[t] : 0;
    int x = v;
    #pragma unroll
    for (int off = 1; off < 64; off <<= 1) {
        int y = __shfl_up(x, off);
        if (lane >= off) x += y;
    }
    __shared__ int ws[4];
    if (lane == 63) ws[wid] = x;
    __syncthreads();
    if (t == 0) {
        int s = 0;
        #pragma unroll
        for (int j = 0; j < 4; j++) { int tmp = ws[j]; ws[j] = s; s += tmp; }
    }
    __syncthreads();
    if (t < SCAN_NB) blk[t] = ws[wid] + x - v;
}

__global__ void k_scan_add(int* __restrict__ row_ptr, const int* __restrict__ blk) {
    int i = blockIdx.x * 256 + threadIdx.x;
    if (i < N_NODES) row_ptr[i] += blk[i >> 8];
    if (i == 0) row_ptr[N_NODES] = N_EDGES;
}

__global__ void k_scatter(const int* __restrict__ src, const int* __restrict__ dst,
                          const int* __restrict__ row_ptr, int* __restrict__ cnt,
                          int* __restrict__ edge_src) {
    int i = blockIdx.x * 256 + threadIdx.x;
    if (i < N_EDGES) {
        int d = dst[i];
        int pos = row_ptr[d] + atomicAdd(&cnt[d], 1);
        edge_src[pos] = src[i];
    }
}

// ---------------- fp32 -> bf16 convert (inputs) ----------------

__global__ void k_tobf16(const float* __restrict__ x, unsigned short* __restrict__ y) {
    int i = blockIdx.x * 256 + threadIdx.x;
    float4 v = ((const float4*)x)[i];
    ushort4 u;
    u.x = f2bf_u(v.x); u.y = f2bf_u(v.y); u.z = f2bf_u(v.z); u.w = f2bf_u(v.w);
    ((ushort4*)y)[i] = u;
}

// ---------------- aggregation: wave per node, 4 edge-slots x 16B/lane ----------------

__global__ void k_aggregate_bf(const unsigned short* __restrict__ feat,
                               const int* __restrict__ row_ptr,
                               const int* __restrict__ edge_src,
                               unsigned short* __restrict__ outb) {
    int w = (blockIdx.x * 256 + threadIdx.x) >> 6;
    int lane = threadIdx.x & 63;
    if (w >= N_NODES) return;
    int slot = lane >> 4, li = lane & 15;
    int beg = row_ptr[w], end = row_ptr[w + 1];
    float acc[8] = {};
    #pragma unroll 1
    for (int e = beg; e < end; e += 4) {
        int eidx = e + slot;
        if (eidx < end) {
            int s = edge_src[eidx];
            short8 v = *(const short8*)((const short*)feat + (size_t)s * EMB + li * 8);
            #pragma unroll
            for (int j = 0; j < 8; j++) acc[j] += bfu2f((unsigned short)v[j]);
        }
    }
    #pragma unroll
    for (int j = 0; j < 8; j++) {
        float t = acc[j];
        t += __shfl_xor(t, 16);
        t += __shfl_xor(t, 32);
        acc[j] = t;
    }
    if (slot == 0) {
        short8 o;
        #pragma unroll
        for (int j = 0; j < 8; j++) o[j] = (short)f2bf_u(acc[j]);
        *(short8*)((short*)outb + (size_t)w * EMB + li * 8) = o;
    }
}

// ---------------- GCN linear via MFMA ----------------

__global__ void __launch_bounds__(256)
k_gcn_mfma(const unsigned short* __restrict__ Ab,   // [M][128] bf16
           const unsigned short* __restrict__ Wb,   // [128][128] bf16
           const float* __restrict__ bias,
           unsigned short* __restrict__ outb,
           int M, int do_tanh) {
    int tid = threadIdx.x;
    int w = tid >> 6, lane = tid & 63;
    int l16 = lane & 15, quad = lane >> 4;
    int rbase = blockIdx.x * 64 + w * 16;
    int arow = rbase + l16;
    if (arow >= M) arow = M - 1;
    const short* Ap = (const short*)Ab + (size_t)arow * 128 + quad * 8;
    const short* Wp = (const short*)Wb;
    f32x4 acc[8] = {};
    #pragma unroll
    for (int ks = 0; ks < 4; ks++) {
        short8 a = *(const short8*)(Ap + ks * 32);
        #pragma unroll
        for (int ct = 0; ct < 8; ct++) {
            short8 b = *(const short8*)(Wp + (size_t)(ct * 16 + l16) * 128 + ks * 32 + quad * 8);
            acc[ct] = __builtin_amdgcn_mfma_f32_16x16x32_bf16(a, b, acc[ct], 0, 0, 0);
        }
    }
    #pragma unroll
    for (int ct = 0; ct < 8; ct++) {
        float bcol = bias[ct * 16 + l16];
        #pragma unroll
        for (int r = 0; r < 4; r++) {
            int row = rbase + quad * 4 + r;
            if (row < M) {
                float v = acc[ct][r] + bcol;
                if (do_tanh) v = tanhf(v);
                outb[(size_t)row * 128 + ct * 16 + l16] = f2bf_u(v);
            }
        }
    }
}

// ---------------- prep: Wpk3 (per-u-slice fragment-linear Wi|Wh) ----------------
// Block usl (0..7) owns h-cols u in [usl*32, usl*32+32) for ALL 4 gates ->
// 128 gate rows R = g*256 + usl*32 + u' over K=384 (k<128: Wi, k>=128: Wh) = 96 KB.
// Fragment (ks 0..11, ct = g*2 + (u'>>4)) at ((usl*12+ks)*8+ct)*512 shorts; element
// lane*8+jj = W[R(ct, l16=lane&15)][ks*32 + (lane>>4)*8 + jj].

__global__ void k_prep(const float* __restrict__ Wi, const float* __restrict__ Wh,
                       const float* __restrict__ bi, const float* __restrict__ bh,
                       const float* __restrict__ W1, const float* __restrict__ W2,
                       unsigned short* __restrict__ Wpk3, float* __restrict__ bsum,
                       unsigned short* __restrict__ W1b, unsigned short* __restrict__ W2b) {
    int idx = blockIdx.x * 256 + threadIdx.x;
    if (idx < 1024 * 384) {
        int R = idx / 384, k = idx - R * 384;
        float v = (k < 128) ? Wi[R * 128 + k] : Wh[R * 256 + (k - 128)];
        int g = R >> 8, u = R & 255;
        int usl = u >> 5, up = u & 31;
        int ct = g * 2 + (up >> 4);
        int l16v = up & 15;
        int ks = k >> 5, kk = k & 31;
        int quad = kk >> 3, jj = kk & 7;
        int lane = quad * 16 + l16v;
        Wpk3[(((size_t)usl * 12 + ks) * 8 + ct) * 512 + lane * 8 + jj] = f2bf_u(v);
    } else if (idx < 1024 * 384 + 1024) {
        int r = idx - 1024 * 384;
        bsum[r] = bi[r] + bh[r];
    } else if (idx < 1024 * 384 + 1024 + 16384) {
        int r = idx - (1024 * 384 + 1024);
        W1b[r] = f2bf_u(W1[r]);
    } else if (idx < 1024 * 384 + 1024 + 32768) {
        int r = idx - (1024 * 384 + 1024 + 16384);
        W2b[r] = f2bf_u(W2[r]);
    }
}

// ---------------- LSTM: weight-stationary, flag-based parallel sync ------------------
// R23: R9 (relaxed atomics) = 198us, 14.9K cyc/step. Known work: MFMA 1.5K + VALU
// 3.4K + LDS ~2.3K + conflicts 1.9K -> ~6-7K residual = serialized sync machinery:
// tid0-spin+broadcast, 8-block RMW contention on one gcnt line, adjacent B0/B4
// barriers, hX atomic-load latency exposed (compiler drains vmcnt at barriers).
// Changes (primitives all R9-proven: relaxed agent atomics + vmcnt(0) ordering):
// (a) per-block FLAGS (64B-strided), release = relaxed STORE (no RMW); wave w polls
//     partner-block w's flag in parallel; B1 joins the 8 verdicts. B0 deleted.
// (b) arrival detection via LDS atomicAdd: 8th wave (after its own vmcnt(0)) does
//     the flag store. B4 deleted. 3 barriers/step.
// (c) GEMM split: x-part (ks 0-3) first; hX atomic loads issued right after B1,
//     consumed by hb ds_writes after x-part (~500cyc hidden under 16 MFMAs);
//     xr prefetch issued after B1b so it drains at B3 (hidden under h-part).

__global__ void __launch_bounds__(512)
__attribute__((amdgpu_waves_per_eu(2, 2)))
k_lstm_ws8(const unsigned short* __restrict__ hn_bf,   // [N_NODES][128] bf16
           const unsigned short* __restrict__ Wpk3,    // packed, see k_prep
           const float* __restrict__ bsum,             // [1024]
           const int* __restrict__ sidx,               // [NSENT][MAXLEN]
           const int* __restrict__ lengths,            // [NSENT]
           unsigned long long* __restrict__ hX,        // [2][NSENT][64] (256 bf16/row)
           int* __restrict__ gflag,                    // [NGRP*8*16] flags (memset 0)
           float* __restrict__ h_last) {               // [NSENT][256] fp32
    __shared__ unsigned short xb[64 * 128];            // 16 KB x_t (chunk-swizzled)
    __shared__ unsigned short hb[64 * 256];            // 32 KB h_t (chunk-swizzled)
    __shared__ float gl[64 * 132];                     // 33 KB gates (independent region)
    __shared__ int nid_sh[NG * 33];                    // 8448 B
    __shared__ int warr;                               // per-step wave-arrival counter

    int tid = threadIdx.x;
    int w = tid >> 6, lane = tid & 63;
    int l16 = lane & 15, quad = lane >> 4;
    int usl = blockIdx.x >> 5;        // u-slice 0..7
    int grp = blockIdx.x & 31;        // sentence group 0..31 (same-XCD under %8 rr)
    int s0 = grp * NG;
    const short* hnp = (const short*)hn_bf;

    int m2 = w >> 2, cp4 = w & 3;     // GEMM wave grid: 2 m-groups x 4 col-groups (32x32)
    int row0 = m2 * 32 + l16, row1 = row0 + 16;

    // ---- prologue: this wave's 24 B-fragments -> REGISTERS (time-invariant) ----
    short8 breg[12][2];
    {
        const short* wsrc = (const short*)Wpk3 + (size_t)usl * 49152 + lane * 8;
        #pragma unroll
        for (int ks = 0; ks < 12; ks++)
            #pragma unroll
            for (int c = 0; c < 2; c++)
                breg[ks][c] = *(const short8*)(wsrc + (size_t)(ks * 8 + cp4 * 2 + c) * 512);
    }
    // bias for this wave's two 16-col tiles (folded into acc init each step)
    float bc0 = bsum[cp4 * 256 + usl * 32 + l16];
    float bc1 = bsum[cp4 * 256 + usl * 32 + 16 + l16];

    // x0 -> xb via async gload (pre-swizzled source)
    #pragma unroll
    for (int i = 0; i < 2; i++) {
        int row = w * 8 + i * 4 + quad;
        int nid = sidx[(size_t)(s0 + row) * MAXLEN + 0];
        int schunk = (l16 & ~7) | ((l16 ^ row) & 7);
        gload_lds16(hnp + (size_t)nid * 128 + schunk * 8,
                    (void*)((char*)xb + (size_t)(w * 8 + i * 4) * 256));
    }
    for (int i = tid; i < NG * 32; i += 512)
        nid_sh[(i >> 5) * 33 + (i & 31)] = sidx[(size_t)(s0 + (i >> 5)) * MAXLEN + (i & 31)];
    for (int i = tid; i < 64 * 128; i += 512) ((unsigned int*)hb)[i] = 0;  // h_{-1}=0
    if (tid == 0) warr = 0;

    // pointwise-thread constants: (psent = tid>>3, 4 h-cols u'0 = (tid&7)*4 ..)
    int psent = tid >> 3, j8 = tid & 7, u0 = j8 * 4;
    int len_reg = lengths[s0 + psent];
    float c_reg[4] = {};

    short8 xr[2];                     // x(t+1) register prefetch

    __syncthreads();                  // prologue staged (drains gload vmcnt)

    #pragma unroll 1
    for (int t = 0; t < MAXLEN; t++) {
        unsigned long long hv[8];
        if (t > 0) {
            // ---- x_t: ds_write prefetched regs (xb(t-1) reads done pre-B3(t-1)) ----
            {
                int row = tid >> 3;
                #pragma unroll
                for (int k = 0; k < 2; k++) {
                    int slot = j8 * 2 + k;
                    *(short8*)(xb + row * 128 + slot * 8) = xr[k];
                }
            }
            // ---- per-wave parallel spin: partner block w finished step t-1 ----
            if (lane == 0) {
                while (__hip_atomic_load(&gflag[(grp * 8 + w) * 16], __ATOMIC_RELAXED,
                                         __HIP_MEMORY_SCOPE_AGENT) < t)
                    __builtin_amdgcn_s_sleep(1);
            }
        }
        __syncthreads();   // B1: joins the 8 spins; staging-writes visible

        // ---- issue h_t atomic loads (hidden under x-part GEMM) ----
        if (t > 0) {
            const unsigned long long* hr = hX + (size_t)(t & 1) * NSENT * 64
                                           + (size_t)(s0 + psent) * 64 + j8 * 8;
            #pragma unroll
            for (int k = 0; k < 8; k++)
                hv[k] = __hip_atomic_load(&hr[k], __ATOMIC_RELAXED,
                                          __HIP_MEMORY_SCOPE_AGENT);
        }

        // ---- x-part GEMM: ks 0..3 (xb only); B in regs; bias in acc init ----
        f32x4 acc00 = {bc0, bc0, bc0, bc0};
        f32x4 acc01 = {bc1, bc1, bc1, bc1};
        f32x4 acc10 = {bc0, bc0, bc0, bc0};
        f32x4 acc11 = {bc1, bc1, bc1, bc1};
        #pragma unroll
        for (int ks = 0; ks < 4; ks++) {
            int kc = ks * 4 + quad;
            short8 a0 = *(const short8*)(xb + row0 * 128 + (((kc & ~7) | ((kc ^ row0) & 7)) * 8));
            short8 a1 = *(const short8*)(xb + row1 * 128 + (((kc & ~7) | ((kc ^ row1) & 7)) * 8));
            acc00 = __builtin_amdgcn_mfma_f32_16x16x32_bf16(a0, breg[ks][0], acc00, 0, 0, 0);
            acc01 = __builtin_amdgcn_mfma_f32_16x16x32_bf16(a0, breg[ks][1], acc01, 0, 0, 0);
            acc10 = __builtin_amdgcn_mfma_f32_16x16x32_bf16(a1, breg[ks][0], acc10, 0, 0, 0);
            acc11 = __builtin_amdgcn_mfma_f32_16x16x32_bf16(a1, breg[ks][1], acc11, 0, 0, 0);
        }

        // ---- h_t -> hb (loads have ~16 MFMAs of cover; auto-waitcnt on hv) ----
        if (t > 0) {
            #pragma unroll
            for (int p = 0; p < 4; p++) {
                int cc = j8 * 4 + p;
                int slot = (cc & ~7) | ((cc ^ psent) & 7);
                union { unsigned long long q[2]; short8 s; } uu;
                uu.q[0] = hv[2 * p]; uu.q[1] = hv[2 * p + 1];
                *(short8*)(hb + psent * 256 + slot * 8) = uu.s;
            }
        }
        __syncthreads();   // B1b: hb visible to all waves

        // ---- issue x(t+1) global->reg prefetch (drains at B3, under h-part) ----
        if (t + 1 < MAXLEN) {
            int row = tid >> 3;
            int nid = nid_sh[row * 33 + (t + 1)];
            #pragma unroll
            for (int k = 0; k < 2; k++) {
                int slot = j8 * 2 + k;
                int c = (slot & ~7) | ((slot ^ row) & 7);
                xr[k] = *(const short8*)(hnp + (size_t)nid * 128 + c * 8);
            }
        }

        // ---- h-part GEMM: ks 4..11 (hb) ----
        #pragma unroll
        for (int ks = 4; ks < 12; ks++) {
            int kc = (ks - 4) * 4 + quad;
            short8 a0 = *(const short8*)(hb + row0 * 256 + (((kc & ~7) | ((kc ^ row0) & 7)) * 8));
            short8 a1 = *(const short8*)(hb + row1 * 256 + (((kc & ~7) | ((kc ^ row1) & 7)) * 8));
            acc00 = __builtin_amdgcn_mfma_f32_16x16x32_bf16(a0, breg[ks][0], acc00, 0, 0, 0);
            acc01 = __builtin_amdgcn_mfma_f32_16x16x32_bf16(a0, breg[ks][1], acc01, 0, 0, 0);
            acc10 = __builtin_amdgcn_mfma_f32_16x16x32_bf16(a1, breg[ks][0], acc10, 0, 0, 0);
            acc11 = __builtin_amdgcn_mfma_f32_16x16x32_bf16(a1, breg[ks][1], acc11, 0, 0, 0);
        }

        // ---- acc (pre-biased) -> gates f32 [64][132] (ncol = g*32+u', g = cp4) ----
        #pragma unroll
        for (int r = 0; r < 4; r++) {
            int se0 = m2 * 32 + quad * 4 + r;
            int se1 = se0 + 16;
            gl[se0 * 132 + cp4 * 32 + l16]      = acc00[r];
            gl[se0 * 132 + cp4 * 32 + 16 + l16] = acc01[r];
            gl[se1 * 132 + cp4 * 32 + l16]      = acc10[r];
            gl[se1 * 132 + cp4 * 32 + 16 + l16] = acc11[r];
        }
        __syncthreads();   // B3: gates ready (drains xr prefetch too)

        // ---- pointwise c/h for (psent, u-cols usl*32+u0 .. +3) ----
        {
            float4 G[4];
            #pragma unroll
            for (int g = 0; g < 4; g++)
                G[g] = *(const float4*)&gl[psent * 132 + g * 32 + u0];
            float hv4[4];
            const float* Gp0 = (const float*)&G[0];
            const float* Gp1 = (const float*)&G[1];
            const float* Gp2 = (const float*)&G[2];
            const float* Gp3 = (const float*)&G[3];
            #pragma unroll
            for (int j = 0; j < 4; j++) {
                float i_ = fsig(Gp0[j]);
                float f_ = fsig(Gp1[j]);
                float g_ = ftanh(Gp2[j]);
                float o_ = fsig(Gp3[j]);
                float c = f_ * c_reg[j] + i_ * g_;
                c_reg[j] = c;
                hv4[j] = o_ * ftanh(c);
            }
            unsigned long long hq =
                  (unsigned long long)f2bf_u(hv4[0])
                | ((unsigned long long)f2bf_u(hv4[1]) << 16)
                | ((unsigned long long)f2bf_u(hv4[2]) << 32)
                | ((unsigned long long)f2bf_u(hv4[3]) << 48);
            unsigned long long* hw = hX + (size_t)((t + 1) & 1) * NSENT * 64
                                     + (size_t)(s0 + psent) * 64 + usl * 8 + j8;
            __hip_atomic_store(hw, hq, __ATOMIC_RELAXED, __HIP_MEMORY_SCOPE_AGENT);
            if (len_reg == t + 1) {
                float4 o4 = make_float4(hv4[0], hv4[1], hv4[2], hv4[3]);
                *(float4*)&h_last[(size_t)(s0 + psent) * 256 + usl * 32 + u0] = o4;
            }
        }

        // ---- arrive: per-wave vmcnt(0) (own hX stores ACK'd), LDS count; the
        //      8th wave publishes the flag (relaxed store, no RMW contention) ----
        if (t + 1 < MAXLEN) {
            WAITVM0();
            if (lane == 0) {
                int old = atomicAdd(&warr, 1);
                if ((old & 7) == 7)
                    __hip_atomic_store(&gflag[(grp * 8 + usl) * 16], t + 1,
                                       __ATOMIC_RELAXED, __HIP_MEMORY_SCOPE_AGENT);
            }
        }
    }
}

// ---------------- classifier ----------------

__global__ void k_classifier(const float* __restrict__ h_last,
                             const float* __restrict__ Wc1, const float* __restrict__ bc1,
                             const float* __restrict__ Wc2, const float* __restrict__ bc2,
                             float* __restrict__ out) {
    int lane = threadIdx.x & 63;
    int wslot = threadIdx.x >> 6;
    int s = blockIdx.x * 4 + wslot;
    __shared__ float e_sh[4][256];
    const float* hr = h_last + (size_t)s * 256;
    #pragma unroll
    for (int i = 0; i < 4; i++) {
        float v = hr[lane + 64 * i];
        e_sh[wslot][lane + 64 * i] = fmaxf(v, 0.f);
    }
    __syncthreads();
    float zpart = 0.f;
    #pragma unroll
    for (int jj = 0; jj < 2; jj++) {
        int j = lane + 64 * jj;
        float a = bc1[j];
        const float4* wr = (const float4*)(Wc1 + (size_t)j * 256);
        #pragma unroll 8
        for (int k4 = 0; k4 < 64; k4++) {
            float4 wv = wr[k4];
            float4 e = *(const float4*)&e_sh[wslot][k4 * 4];
            a += wv.x * e.x + wv.y * e.y + wv.z * e.z + wv.w * e.w;
        }
        a = fmaxf(a, 0.f);
        zpart += a * Wc2[j];
    }
    #pragma unroll
    for (int off = 32; off > 0; off >>= 1) zpart += __shfl_down(zpart, off);
    if (lane == 0) out[s] = zpart + bc2[0];
}

// ---------------- launcher ----------------

extern "C" void kernel_launch(void* const* d_in, const int* in_sizes, int n_in,
                              void* d_out, int out_size, void* d_ws, size_t ws_size,
                              hipStream_t stream) {
    const float* inputs = (const float*)d_in[0];
    const float* W1  = (const float*)d_in[1];
    const float* b1  = (const float*)d_in[2];
    const float* W2  = (const float*)d_in[3];
    const float* b2  = (const float*)d_in[4];
    const float* Wi  = (const float*)d_in[5];
    const float* Wh  = (const float*)d_in[6];
    const float* bi  = (const float*)d_in[7];
    const float* bh  = (const float*)d_in[8];
    const float* Wc1 = (const float*)d_in[9];
    const float* bc1 = (const float*)d_in[10];
    const float* Wc2 = (const float*)d_in[11];
    const float* bc2 = (const float*)d_in[12];
    const int* src      = (const int*)d_in[13];
    const int* dst      = (const int*)d_in[14];
    const int* sidx     = (const int*)d_in[15];
    const int* lengths  = (const int*)d_in[16];
    float* out = (float*)d_out;

    char* ws = (char*)d_ws;
    size_t off = 0;
    auto alloc = [&](size_t bytes) -> void* {
        void* p = ws + off;
        off = (off + bytes + 255) & ~(size_t)255;
        return p;
    };
    unsigned short* in_bf  = (unsigned short*)alloc(2 * (size_t)N_NODES * EMB);
    unsigned short* agg_bf = (unsigned short*)alloc(2 * (size_t)N_NODES * EMB);
    unsigned short* h_bf   = (unsigned short*)alloc(2 * (size_t)N_NODES * EMB);
    unsigned short* hn_bf  = (unsigned short*)alloc(2 * (size_t)N_NODES * EMB);
    int*   row_ptr  = (int*)alloc(sizeof(int) * (N_NODES + 1));
    int*   cnt      = (int*)alloc(sizeof(int) * N_NODES);
    int*   blk      = (int*)alloc(sizeof(int) * SCAN_NB);
    int*   edge_src = (int*)alloc(sizeof(int) * N_EDGES);
    unsigned short* Wpk3 = (unsigned short*)alloc(2 * 8 * 12 * 8 * 512);  // 768 KB
    unsigned short* W1b  = (unsigned short*)alloc(2 * 128 * 128);
    unsigned short* W2b  = (unsigned short*)alloc(2 * 128 * 128);
    float* bsum     = (float*)alloc(sizeof(float) * 1024);
    float* hlast    = (float*)alloc(sizeof(float) * NSENT * LH);
    unsigned long long* hX = (unsigned long long*)alloc(2 * (size_t)NSENT * 64 * 8);  // 2 MB
    int* gflag      = (int*)alloc(sizeof(int) * NGRP * 8 * 16);

    // weight prep (independent of everything else)
    k_prep<<<(1024 * 384 + 1024 + 32768 + 255) / 256, 256, 0, stream>>>(
        Wi, Wh, bi, bh, W1, W2, Wpk3, bsum, W1b, W2b);

    // LSTM exchange buffers: flags = 0 (hX zeroed for hygiene)
    hipMemsetAsync(hX, 0, 2 * (size_t)NSENT * 64 * 8, stream);
    hipMemsetAsync(gflag, 0, sizeof(int) * NGRP * 8 * 16, stream);

    // CSR build
    hipMemsetAsync(cnt, 0, sizeof(int) * N_NODES, stream);
    k_hist<<<(N_EDGES + 255) / 256, 256, 0, stream>>>(dst, cnt);
    k_scan_blk<<<SCAN_NB, 256, 0, stream>>>(cnt, row_ptr, blk);
    k_scan_tot<<<1, 256, 0, stream>>>(blk);
    k_scan_add<<<SCAN_NB, 256, 0, stream>>>(row_ptr, blk);
    hipMemsetAsync(cnt, 0, sizeof(int) * N_NODES, stream);
    k_scatter<<<(N_EDGES + 255) / 256, 256, 0, stream>>>(src, dst, row_ptr, cnt, edge_src);

    // GCN (bf16 path)
    k_tobf16<<<(N_NODES * EMB / 4 + 255) / 256, 256, 0, stream>>>(inputs, in_bf);
    k_aggregate_bf<<<(N_NODES * 64) / 256, 256, 0, stream>>>(in_bf, row_ptr, edge_src, agg_bf);
    k_gcn_mfma<<<(N_NODES + 63) / 64, 256, 0, stream>>>(agg_bf, W1b, b1, h_bf, N_NODES, 1);
    k_aggregate_bf<<<(N_NODES * 64) / 256, 256, 0, stream>>>(h_bf, row_ptr, edge_src, agg_bf);
    k_gcn_mfma<<<(N_NODES + 63) / 64, 256, 0, stream>>>(agg_bf, W2b, b2, hn_bf, N_NODES, 0);

    // LSTM: weight-stationary (B in VGPRs), flag-based parallel sync
    k_lstm_ws8<<<NGRP * 8, 512, 0, stream>>>(hn_bf, Wpk3, bsum, sidx, lengths,
                                             hX, gflag, hlast);

    // classifier
    k_classifier<<<NSENT / 4, 256, 0, stream>>>(hlast, Wc1, bc1, Wc2, bc2, out);
}

// Round 11
// 507.934 us; speedup vs baseline: 1.0786x; 1.0786x over previous
//
#include <hip/hip_runtime.h>
#include <hip/hip_bf16.h>
#include <math.h>

#define N_NODES 50000
#define N_EDGES 800000
#define EMB 128
#define LH 256
#define NSENT 2048
#define MAXLEN 32
#define SCAN_NB 196   // ceil(50000/256)
#define NG 64         // sentences per group
#define NGRP 32       // groups (NSENT/NG)

typedef __attribute__((ext_vector_type(8))) short short8;
typedef __attribute__((ext_vector_type(4))) float f32x4;

__device__ __forceinline__ unsigned short f2bf_u(float f) {
    __hip_bfloat16 h = __float2bfloat16(f);
    return *reinterpret_cast<unsigned short*>(&h);
}
__device__ __forceinline__ float bfu2f(unsigned short u) {
    unsigned int x = ((unsigned int)u) << 16;
    return __uint_as_float(x);
}

// fast activations: ~1e-7 abs error, negligible vs bf16 h-state rounding (2^-9)
__device__ __forceinline__ float fsig(float x) {
    return 1.f / (1.f + __expf(-x));
}
__device__ __forceinline__ float ftanh(float x) {
    return 1.f - 2.f / (__expf(2.f * x) + 1.f);
}

#define WAITVM0() __builtin_amdgcn_s_waitcnt(0xF70)   // vmcnt(0)

// async global->LDS, 16B/lane; gsrc per-lane, LDS dst = wave-uniform base + lane*16
__device__ __forceinline__ void gload_lds16(const void* gsrc, void* ldst) {
    __builtin_amdgcn_global_load_lds(
        (const __attribute__((address_space(1))) unsigned int*)gsrc,
        (__attribute__((address_space(3))) unsigned int*)ldst, 16, 0, 0);
}

// ---------------- CSR build ----------------

__global__ void k_hist(const int* __restrict__ dst, int* __restrict__ cnt) {
    int i = blockIdx.x * 256 + threadIdx.x;
    if (i < N_EDGES) atomicAdd(&cnt[dst[i]], 1);
}

__global__ void k_scan_blk(const int* __restrict__ cnt, int* __restrict__ row_ptr,
                           int* __restrict__ blk) {
    int b = blockIdx.x, t = threadIdx.x;
    int i = b * 256 + t;
    int lane = t & 63, wid = t >> 6;
    int v = (i < N_NODES) ? cnt[i] : 0;
    int x = v;
    #pragma unroll
    for (int off = 1; off < 64; off <<= 1) {
        int y = __shfl_up(x, off);
        if (lane >= off) x += y;
    }
    __shared__ int ws[4];
    if (lane == 63) ws[wid] = x;
    __syncthreads();
    if (t == 0) {
        int s = 0;
        #pragma unroll
        for (int j = 0; j < 4; j++) { int tmp = ws[j]; ws[j] = s; s += tmp; }
        blk[b] = s;
    }
    __syncthreads();
    if (i < N_NODES) row_ptr[i] = ws[wid] + x - v;
}

__global__ void k_scan_tot(int* __restrict__ blk) {
    int t = threadIdx.x;
    int lane = t & 63, wid = t >> 6;
    int v = (t < SCAN_NB) ? blk[t] : 0;
    int x = v;
    #pragma unroll
    for (int off = 1; off < 64; off <<= 1) {
        int y = __shfl_up(x, off);
        if (lane >= off) x += y;
    }
    __shared__ int ws[4];
    if (lane == 63) ws[wid] = x;
    __syncthreads();
    if (t == 0) {
        int s = 0;
        #pragma unroll
        for (int j = 0; j < 4; j++) { int tmp = ws[j]; ws[j] = s; s += tmp; }
    }
    __syncthreads();
    if (t < SCAN_NB) blk[t] = ws[wid] + x - v;
}

__global__ void k_scan_add(int* __restrict__ row_ptr, const int* __restrict__ blk) {
    int i = blockIdx.x * 256 + threadIdx.x;
    if (i < N_NODES) row_ptr[i] += blk[i >> 8];
    if (i == 0) row_ptr[N_NODES] = N_EDGES;
}

__global__ void k_scatter(const int* __restrict__ src, const int* __restrict__ dst,
                          const int* __restrict__ row_ptr, int* __restrict__ cnt,
                          int* __restrict__ edge_src) {
    int i = blockIdx.x * 256 + threadIdx.x;
    if (i < N_EDGES) {
        int d = dst[i];
        int pos = row_ptr[d] + atomicAdd(&cnt[d], 1);
        edge_src[pos] = src[i];
    }
}

// ---------------- fp32 -> bf16 convert (inputs) ----------------

__global__ void k_tobf16(const float* __restrict__ x, unsigned short* __restrict__ y) {
    int i = blockIdx.x * 256 + threadIdx.x;
    float4 v = ((const float4*)x)[i];
    ushort4 u;
    u.x = f2bf_u(v.x); u.y = f2bf_u(v.y); u.z = f2bf_u(v.z); u.w = f2bf_u(v.w);
    ((ushort4*)y)[i] = u;
}

// ---------------- aggregation: wave per node, 2-deep gather pipeline ----------------
// R24: the gather chain was serial (edge_src load -> row load -> accumulate) with one
// row-group in flight. Pipeline depth 2: 4 row-loads + 2 index-loads in flight while
// accumulating the previous two groups -> 2x memory-level parallelism on the only
// latency-bound gather kernel in the pipeline.

__global__ void k_aggregate_bf(const unsigned short* __restrict__ feat,
                               const int* __restrict__ row_ptr,
                               const int* __restrict__ edge_src,
                               unsigned short* __restrict__ outb) {
    int w = (blockIdx.x * 256 + threadIdx.x) >> 6;
    int lane = threadIdx.x & 63;
    if (w >= N_NODES) return;
    int slot = lane >> 4, li = lane & 15;
    int beg = row_ptr[w], end = row_ptr[w + 1];
    float acc[8] = {};
    short8 vA = {}, vB = {};
    {
        int eA = beg + slot, eB = beg + 4 + slot;
        int sA = (eA < end) ? edge_src[eA] : -1;
        int sB = (eB < end) ? edge_src[eB] : -1;
        if (sA >= 0) vA = *(const short8*)((const short*)feat + (size_t)sA * EMB + li * 8);
        if (sB >= 0) vB = *(const short8*)((const short*)feat + (size_t)sB * EMB + li * 8);
    }
    #pragma unroll 1
    for (int e = beg; e < end; e += 8) {
        // prefetch groups e+8, e+12
        int eA2 = e + 8 + slot, eB2 = e + 12 + slot;
        int sA2 = (eA2 < end) ? edge_src[eA2] : -1;
        int sB2 = (eB2 < end) ? edge_src[eB2] : -1;
        short8 vA2 = {}, vB2 = {};
        if (sA2 >= 0) vA2 = *(const short8*)((const short*)feat + (size_t)sA2 * EMB + li * 8);
        if (sB2 >= 0) vB2 = *(const short8*)((const short*)feat + (size_t)sB2 * EMB + li * 8);
        // accumulate current groups
        if (e + slot < end) {
            #pragma unroll
            for (int j = 0; j < 8; j++) acc[j] += bfu2f((unsigned short)vA[j]);
        }
        if (e + 4 + slot < end) {
            #pragma unroll
            for (int j = 0; j < 8; j++) acc[j] += bfu2f((unsigned short)vB[j]);
        }
        vA = vA2; vB = vB2;
    }
    #pragma unroll
    for (int j = 0; j < 8; j++) {
        float t = acc[j];
        t += __shfl_xor(t, 16);
        t += __shfl_xor(t, 32);
        acc[j] = t;
    }
    if (slot == 0) {
        short8 o;
        #pragma unroll
        for (int j = 0; j < 8; j++) o[j] = (short)f2bf_u(acc[j]);
        *(short8*)((short*)outb + (size_t)w * EMB + li * 8) = o;
    }
}

// ---------------- GCN linear via MFMA ----------------

__global__ void __launch_bounds__(256)
k_gcn_mfma(const unsigned short* __restrict__ Ab,   // [M][128] bf16
           const unsigned short* __restrict__ Wb,   // [128][128] bf16
           const float* __restrict__ bias,
           unsigned short* __restrict__ outb,
           int M, int do_tanh) {
    int tid = threadIdx.x;
    int w = tid >> 6, lane = tid & 63;
    int l16 = lane & 15, quad = lane >> 4;
    int rbase = blockIdx.x * 64 + w * 16;
    int arow = rbase + l16;
    if (arow >= M) arow = M - 1;
    const short* Ap = (const short*)Ab + (size_t)arow * 128 + quad * 8;
    const short* Wp = (const short*)Wb;
    f32x4 acc[8] = {};
    #pragma unroll
    for (int ks = 0; ks < 4; ks++) {
        short8 a = *(const short8*)(Ap + ks * 32);
        #pragma unroll
        for (int ct = 0; ct < 8; ct++) {
            short8 b = *(const short8*)(Wp + (size_t)(ct * 16 + l16) * 128 + ks * 32 + quad * 8);
            acc[ct] = __builtin_amdgcn_mfma_f32_16x16x32_bf16(a, b, acc[ct], 0, 0, 0);
        }
    }
    #pragma unroll
    for (int ct = 0; ct < 8; ct++) {
        float bcol = bias[ct * 16 + l16];
        #pragma unroll
        for (int r = 0; r < 4; r++) {
            int row = rbase + quad * 4 + r;
            if (row < M) {
                float v = acc[ct][r] + bcol;
                if (do_tanh) v = tanhf(v);
                outb[(size_t)row * 128 + ct * 16 + l16] = f2bf_u(v);
            }
        }
    }
}

// ---------------- prep: Wpk3 (per-u-slice fragment-linear Wi|Wh) ----------------
// Block usl (0..7) owns h-cols u in [usl*32, usl*32+32) for ALL 4 gates ->
// 128 gate rows R = g*256 + usl*32 + u' over K=384 (k<128: Wi, k>=128: Wh) = 96 KB.
// Fragment (ks 0..11, ct = g*2 + (u'>>4)) at ((usl*12+ks)*8+ct)*512 shorts; element
// lane*8+jj = W[R(ct, l16=lane&15)][ks*32 + (lane>>4)*8 + jj].

__global__ void k_prep(const float* __restrict__ Wi, const float* __restrict__ Wh,
                       const float* __restrict__ bi, const float* __restrict__ bh,
                       const float* __restrict__ W1, const float* __restrict__ W2,
                       unsigned short* __restrict__ Wpk3, float* __restrict__ bsum,
                       unsigned short* __restrict__ W1b, unsigned short* __restrict__ W2b) {
    int idx = blockIdx.x * 256 + threadIdx.x;
    if (idx < 1024 * 384) {
        int R = idx / 384, k = idx - R * 384;
        float v = (k < 128) ? Wi[R * 128 + k] : Wh[R * 256 + (k - 128)];
        int g = R >> 8, u = R & 255;
        int usl = u >> 5, up = u & 31;
        int ct = g * 2 + (up >> 4);
        int l16v = up & 15;
        int ks = k >> 5, kk = k & 31;
        int quad = kk >> 3, jj = kk & 7;
        int lane = quad * 16 + l16v;
        Wpk3[(((size_t)usl * 12 + ks) * 8 + ct) * 512 + lane * 8 + jj] = f2bf_u(v);
    } else if (idx < 1024 * 384 + 1024) {
        int r = idx - 1024 * 384;
        bsum[r] = bi[r] + bh[r];
    } else if (idx < 1024 * 384 + 1024 + 16384) {
        int r = idx - (1024 * 384 + 1024);
        W1b[r] = f2bf_u(W1[r]);
    } else if (idx < 1024 * 384 + 1024 + 32768) {
        int r = idx - (1024 * 384 + 1024 + 16384);
        W2b[r] = f2bf_u(W2[r]);
    }
}

// ---------------- LSTM: weight-stationary, R9 sync, spin AFTER x-part ----------------
// R24 post-mortem: R10's bundle (per-wave flags, LDS arrival, GEMM split) regressed
// 198->209us -- sync DETECTION isn't the lever; R9's tid0-spin + single counter was
// near-optimal. Residual = latency chain {store-ACK, publish->observe, hv-load RT}
// serialized against compute. Single change vs R9: the x-part GEMM (ks0-3, depends
// only on block-local x_t) runs BEFORE the spin -> publish->observe latency hides
// under 16 MFMAs + 8 ds_reads. Consequences: x_{t+1} ds_write moves to the tail
// (before the arrive barrier Bx, which orders it vs next iter's x-part), xr issue
// moves to the iteration top. Barrier count unchanged (4/step: Bspin, Bh, B3, Bx).
// All other mechanics byte-identical to R9 (relaxed atomics, WAITVM0 ordering,
// tid0 release fetch_add, B-weights in registers, bias-folded acc init).

__global__ void __launch_bounds__(512)
__attribute__((amdgpu_waves_per_eu(2, 2)))
k_lstm_ws8(const unsigned short* __restrict__ hn_bf,   // [N_NODES][128] bf16
           const unsigned short* __restrict__ Wpk3,    // packed, see k_prep
           const float* __restrict__ bsum,             // [1024]
           const int* __restrict__ sidx,               // [NSENT][MAXLEN]
           const int* __restrict__ lengths,            // [NSENT]
           unsigned long long* __restrict__ hX,        // [2][NSENT][64] (256 bf16/row)
           int* __restrict__ gcnt,                     // [NGRP*32] arrival ctrs (memset 0)
           float* __restrict__ h_last) {               // [NSENT][256] fp32
    __shared__ unsigned short xb[64 * 128];            // 16 KB x_t (chunk-swizzled)
    __shared__ unsigned short hb[64 * 256];            // 32 KB h_t (chunk-swizzled)
    __shared__ float gl[64 * 132];                     // 33 KB gates (independent region)
    __shared__ int nid_sh[NG * 33];                    // 8448 B

    int tid = threadIdx.x;
    int w = tid >> 6, lane = tid & 63;
    int l16 = lane & 15, quad = lane >> 4;
    int usl = blockIdx.x >> 5;        // u-slice 0..7
    int grp = blockIdx.x & 31;        // sentence group 0..31 (same-XCD under %8 rr)
    int s0 = grp * NG;
    const short* hnp = (const short*)hn_bf;

    int m2 = w >> 2, cp4 = w & 3;     // GEMM wave grid: 2 m-groups x 4 col-groups (32x32)
    int row0 = m2 * 32 + l16, row1 = row0 + 16;

    // ---- prologue: this wave's 24 B-fragments -> REGISTERS (time-invariant) ----
    short8 breg[12][2];
    {
        const short* wsrc = (const short*)Wpk3 + (size_t)usl * 49152 + lane * 8;
        #pragma unroll
        for (int ks = 0; ks < 12; ks++)
            #pragma unroll
            for (int c = 0; c < 2; c++)
                breg[ks][c] = *(const short8*)(wsrc + (size_t)(ks * 8 + cp4 * 2 + c) * 512);
    }
    // bias for this wave's two 16-col tiles (folded into acc init each step)
    float bc0 = bsum[cp4 * 256 + usl * 32 + l16];
    float bc1 = bsum[cp4 * 256 + usl * 32 + 16 + l16];

    // x0 -> xb via async gload (pre-swizzled source)
    #pragma unroll
    for (int i = 0; i < 2; i++) {
        int row = w * 8 + i * 4 + quad;
        int nid = sidx[(size_t)(s0 + row) * MAXLEN + 0];
        int schunk = (l16 & ~7) | ((l16 ^ row) & 7);
        gload_lds16(hnp + (size_t)nid * 128 + schunk * 8,
                    (void*)((char*)xb + (size_t)(w * 8 + i * 4) * 256));
    }
    for (int i = tid; i < NG * 32; i += 512)
        nid_sh[(i >> 5) * 33 + (i & 31)] = sidx[(size_t)(s0 + (i >> 5)) * MAXLEN + (i & 31)];
    for (int i = tid; i < 64 * 128; i += 512) ((unsigned int*)hb)[i] = 0;  // h_{-1}=0

    // pointwise-thread constants: (psent = tid>>3, 4 h-cols u'0 = (tid&7)*4 ..)
    int psent = tid >> 3, j8 = tid & 7, u0 = j8 * 4;
    int len_reg = lengths[s0 + psent];
    float c_reg[4] = {};

    short8 xr[2];                     // x(t+1) register prefetch

    __syncthreads();                  // prologue staged (drains gload vmcnt)

    #pragma unroll 1
    for (int t = 0; t < MAXLEN; t++) {
        // ---- issue x(t+1) global->reg prefetch (consumed at this iter's tail) ----
        if (t + 1 < MAXLEN) {
            int row = tid >> 3;
            int nid = nid_sh[row * 33 + (t + 1)];
            #pragma unroll
            for (int k = 0; k < 2; k++) {
                int slot = j8 * 2 + k;
                int c = (slot & ~7) | ((slot ^ row) & 7);
                xr[k] = *(const short8*)(hnp + (size_t)nid * 128 + c * 8);
            }
        }

        // ---- x-part GEMM: ks 0..3 (xb only) -- runs BEFORE the spin ----
        f32x4 acc00 = {bc0, bc0, bc0, bc0};
        f32x4 acc01 = {bc1, bc1, bc1, bc1};
        f32x4 acc10 = {bc0, bc0, bc0, bc0};
        f32x4 acc11 = {bc1, bc1, bc1, bc1};
        #pragma unroll
        for (int ks = 0; ks < 4; ks++) {
            int kc = ks * 4 + quad;
            short8 a0 = *(const short8*)(xb + row0 * 128 + (((kc & ~7) | ((kc ^ row0) & 7)) * 8));
            short8 a1 = *(const short8*)(xb + row1 * 128 + (((kc & ~7) | ((kc ^ row1) & 7)) * 8));
            acc00 = __builtin_amdgcn_mfma_f32_16x16x32_bf16(a0, breg[ks][0], acc00, 0, 0, 0);
            acc01 = __builtin_amdgcn_mfma_f32_16x16x32_bf16(a0, breg[ks][1], acc01, 0, 0, 0);
            acc10 = __builtin_amdgcn_mfma_f32_16x16x32_bf16(a1, breg[ks][0], acc10, 0, 0, 0);
            acc11 = __builtin_amdgcn_mfma_f32_16x16x32_bf16(a1, breg[ks][1], acc11, 0, 0, 0);
        }

        // ---- spin (publish->observe hidden under x-part) + h exchange ----
        if (t > 0) {
            if (tid == 0) {
                while (__hip_atomic_load(&gcnt[grp * 32], __ATOMIC_RELAXED,
                                         __HIP_MEMORY_SCOPE_AGENT) < 8 * t)
                    __builtin_amdgcn_s_sleep(1);
            }
            __syncthreads();   // Bspin: broadcast
            {
                const unsigned long long* hr = hX + (size_t)(t & 1) * NSENT * 64
                                               + (size_t)(s0 + psent) * 64 + j8 * 8;
                unsigned long long hv[8];
                #pragma unroll
                for (int k = 0; k < 8; k++)
                    hv[k] = __hip_atomic_load(&hr[k], __ATOMIC_RELAXED,
                                              __HIP_MEMORY_SCOPE_AGENT);
                #pragma unroll
                for (int p = 0; p < 4; p++) {
                    int cc = j8 * 4 + p;
                    int slot = (cc & ~7) | ((cc ^ psent) & 7);
                    union { unsigned long long q[2]; short8 s; } uu;
                    uu.q[0] = hv[2 * p]; uu.q[1] = hv[2 * p + 1];
                    *(short8*)(hb + psent * 256 + slot * 8) = uu.s;
                }
            }
        }
        __syncthreads();   // Bh: hb visible to all waves

        // ---- h-part GEMM: ks 4..11 (hb) ----
        #pragma unroll
        for (int ks = 4; ks < 12; ks++) {
            int kc = (ks - 4) * 4 + quad;
            short8 a0 = *(const short8*)(hb + row0 * 256 + (((kc & ~7) | ((kc ^ row0) & 7)) * 8));
            short8 a1 = *(const short8*)(hb + row1 * 256 + (((kc & ~7) | ((kc ^ row1) & 7)) * 8));
            acc00 = __builtin_amdgcn_mfma_f32_16x16x32_bf16(a0, breg[ks][0], acc00, 0, 0, 0);
            acc01 = __builtin_amdgcn_mfma_f32_16x16x32_bf16(a0, breg[ks][1], acc01, 0, 0, 0);
            acc10 = __builtin_amdgcn_mfma_f32_16x16x32_bf16(a1, breg[ks][0], acc10, 0, 0, 0);
            acc11 = __builtin_amdgcn_mfma_f32_16x16x32_bf16(a1, breg[ks][1], acc11, 0, 0, 0);
        }

        // ---- acc (pre-biased) -> gates f32 [64][132] (ncol = g*32+u', g = cp4) ----
        #pragma unroll
        for (int r = 0; r < 4; r++) {
            int se0 = m2 * 32 + quad * 4 + r;
            int se1 = se0 + 16;
            gl[se0 * 132 + cp4 * 32 + l16]      = acc00[r];
            gl[se0 * 132 + cp4 * 32 + 16 + l16] = acc01[r];
            gl[se1 * 132 + cp4 * 32 + l16]      = acc10[r];
            gl[se1 * 132 + cp4 * 32 + 16 + l16] = acc11[r];
        }
        __syncthreads();   // B3: gates ready

        // ---- pointwise c/h for (psent, u-cols usl*32+u0 .. +3) ----
        {
            float4 G[4];
            #pragma unroll
            for (int g = 0; g < 4; g++)
                G[g] = *(const float4*)&gl[psent * 132 + g * 32 + u0];
            float hv4[4];
            const float* Gp0 = (const float*)&G[0];
            const float* Gp1 = (const float*)&G[1];
            const float* Gp2 = (const float*)&G[2];
            const float* Gp3 = (const float*)&G[3];
            #pragma unroll
            for (int j = 0; j < 4; j++) {
                float i_ = fsig(Gp0[j]);
                float f_ = fsig(Gp1[j]);
                float g_ = ftanh(Gp2[j]);
                float o_ = fsig(Gp3[j]);
                float c = f_ * c_reg[j] + i_ * g_;
                c_reg[j] = c;
                hv4[j] = o_ * ftanh(c);
            }
            unsigned long long hq =
                  (unsigned long long)f2bf_u(hv4[0])
                | ((unsigned long long)f2bf_u(hv4[1]) << 16)
                | ((unsigned long long)f2bf_u(hv4[2]) << 32)
                | ((unsigned long long)f2bf_u(hv4[3]) << 48);
            unsigned long long* hw = hX + (size_t)((t + 1) & 1) * NSENT * 64
                                     + (size_t)(s0 + psent) * 64 + usl * 8 + j8;
            __hip_atomic_store(hw, hq, __ATOMIC_RELAXED, __HIP_MEMORY_SCOPE_AGENT);
            if (len_reg == t + 1) {
                float4 o4 = make_float4(hv4[0], hv4[1], hv4[2], hv4[3]);
                *(float4*)&h_last[(size_t)(s0 + psent) * 256 + usl * 32 + u0] = o4;
            }
        }

        // ---- tail: stage x(t+1) into xb, ACK hX stores, arrive ----
        if (t + 1 < MAXLEN) {
            {
                int row = tid >> 3;
                #pragma unroll
                for (int k = 0; k < 2; k++) {
                    int slot = j8 * 2 + k;
                    *(short8*)(xb + row * 128 + slot * 8) = xr[k];
                }
            }
            WAITVM0();         // hX stores ACK'd at coherence point (xr long drained)
            __syncthreads();   // Bx: joins; xb visible for next iter's x-part
            if (tid == 0)
                __hip_atomic_fetch_add(&gcnt[grp * 32], 1, __ATOMIC_RELAXED,
                                       __HIP_MEMORY_SCOPE_AGENT);
        }
    }
}

// ---------------- classifier ----------------

__global__ void k_classifier(const float* __restrict__ h_last,
                             const float* __restrict__ Wc1, const float* __restrict__ bc1,
                             const float* __restrict__ Wc2, const float* __restrict__ bc2,
                             float* __restrict__ out) {
    int lane = threadIdx.x & 63;
    int wslot = threadIdx.x >> 6;
    int s = blockIdx.x * 4 + wslot;
    __shared__ float e_sh[4][256];
    const float* hr = h_last + (size_t)s * 256;
    #pragma unroll
    for (int i = 0; i < 4; i++) {
        float v = hr[lane + 64 * i];
        e_sh[wslot][lane + 64 * i] = fmaxf(v, 0.f);
    }
    __syncthreads();
    float zpart = 0.f;
    #pragma unroll
    for (int jj = 0; jj < 2; jj++) {
        int j = lane + 64 * jj;
        float a = bc1[j];
        const float4* wr = (const float4*)(Wc1 + (size_t)j * 256);
        #pragma unroll 8
        for (int k4 = 0; k4 < 64; k4++) {
            float4 wv = wr[k4];
            float4 e = *(const float4*)&e_sh[wslot][k4 * 4];
            a += wv.x * e.x + wv.y * e.y + wv.z * e.z + wv.w * e.w;
        }
        a = fmaxf(a, 0.f);
        zpart += a * Wc2[j];
    }
    #pragma unroll
    for (int off = 32; off > 0; off >>= 1) zpart += __shfl_down(zpart, off);
    if (lane == 0) out[s] = zpart + bc2[0];
}

// ---------------- launcher ----------------

extern "C" void kernel_launch(void* const* d_in, const int* in_sizes, int n_in,
                              void* d_out, int out_size, void* d_ws, size_t ws_size,
                              hipStream_t stream) {
    const float* inputs = (const float*)d_in[0];
    const float* W1  = (const float*)d_in[1];
    const float* b1  = (const float*)d_in[2];
    const float* W2  = (const float*)d_in[3];
    const float* b2  = (const float*)d_in[4];
    const float* Wi  = (const float*)d_in[5];
    const float* Wh  = (const float*)d_in[6];
    const float* bi  = (const float*)d_in[7];
    const float* bh  = (const float*)d_in[8];
    const float* Wc1 = (const float*)d_in[9];
    const float* bc1 = (const float*)d_in[10];
    const float* Wc2 = (const float*)d_in[11];
    const float* bc2 = (const float*)d_in[12];
    const int* src      = (const int*)d_in[13];
    const int* dst      = (const int*)d_in[14];
    const int* sidx     = (const int*)d_in[15];
    const int* lengths  = (const int*)d_in[16];
    float* out = (float*)d_out;

    char* ws = (char*)d_ws;
    size_t off = 0;
    auto alloc = [&](size_t bytes) -> void* {
        void* p = ws + off;
        off = (off + bytes + 255) & ~(size_t)255;
        return p;
    };
    unsigned short* in_bf  = (unsigned short*)alloc(2 * (size_t)N_NODES * EMB);
    unsigned short* agg_bf = (unsigned short*)alloc(2 * (size_t)N_NODES * EMB);
    unsigned short* h_bf   = (unsigned short*)alloc(2 * (size_t)N_NODES * EMB);
    unsigned short* hn_bf  = (unsigned short*)alloc(2 * (size_t)N_NODES * EMB);
    int*   row_ptr  = (int*)alloc(sizeof(int) * (N_NODES + 1));
    int*   cnt      = (int*)alloc(sizeof(int) * N_NODES);
    int*   blk      = (int*)alloc(sizeof(int) * SCAN_NB);
    int*   edge_src = (int*)alloc(sizeof(int) * N_EDGES);
    unsigned short* Wpk3 = (unsigned short*)alloc(2 * 8 * 12 * 8 * 512);  // 768 KB
    unsigned short* W1b  = (unsigned short*)alloc(2 * 128 * 128);
    unsigned short* W2b  = (unsigned short*)alloc(2 * 128 * 128);
    float* bsum     = (float*)alloc(sizeof(float) * 1024);
    float* hlast    = (float*)alloc(sizeof(float) * NSENT * LH);
    unsigned long long* hX = (unsigned long long*)alloc(2 * (size_t)NSENT * 64 * 8);  // 2 MB
    int* gcnt       = (int*)alloc(sizeof(int) * NGRP * 32);

    // weight prep (independent of everything else)
    k_prep<<<(1024 * 384 + 1024 + 32768 + 255) / 256, 256, 0, stream>>>(
        Wi, Wh, bi, bh, W1, W2, Wpk3, bsum, W1b, W2b);

    // LSTM exchange buffers: arrival counters = 0 (hX zeroed for hygiene)
    hipMemsetAsync(hX, 0, 2 * (size_t)NSENT * 64 * 8, stream);
    hipMemsetAsync(gcnt, 0, sizeof(int) * NGRP * 32, stream);

    // CSR build
    hipMemsetAsync(cnt, 0, sizeof(int) * N_NODES, stream);
    k_hist<<<(N_EDGES + 255) / 256, 256, 0, stream>>>(dst, cnt);
    k_scan_blk<<<SCAN_NB, 256, 0, stream>>>(cnt, row_ptr, blk);
    k_scan_tot<<<1, 256, 0, stream>>>(blk);
    k_scan_add<<<SCAN_NB, 256, 0, stream>>>(row_ptr, blk);
    hipMemsetAsync(cnt, 0, sizeof(int) * N_NODES, stream);
    k_scatter<<<(N_EDGES + 255) / 256, 256, 0, stream>>>(src, dst, row_ptr, cnt, edge_src);

    // GCN (bf16 path)
    k_tobf16<<<(N_NODES * EMB / 4 + 255) / 256, 256, 0, stream>>>(inputs, in_bf);
    k_aggregate_bf<<<(N_NODES * 64) / 256, 256, 0, stream>>>(in_bf, row_ptr, edge_src, agg_bf);
    k_gcn_mfma<<<(N_NODES + 63) / 64, 256, 0, stream>>>(agg_bf, W1b, b1, h_bf, N_NODES, 1);
    k_aggregate_bf<<<(N_NODES * 64) / 256, 256, 0, stream>>>(h_bf, row_ptr, edge_src, agg_bf);
    k_gcn_mfma<<<(N_NODES + 63) / 64, 256, 0, stream>>>(agg_bf, W2b, b2, hn_bf, N_NODES, 0);

    // LSTM: weight-stationary (B in VGPRs), R9 sync, spin-after-x-part
    k_lstm_ws8<<<NGRP * 8, 512, 0, stream>>>(hn_bf, Wpk3, bsum, sidx, lengths,
                                             hX, gcnt, hlast);

    // classifier
    k_classifier<<<NSENT / 4, 256, 0, stream>>>(hlast, Wc1, bc1, Wc2, bc2, out);
}

// Round 12
// 503.265 us; speedup vs baseline: 1.0886x; 1.0093x over previous
//
#include <hip/hip_runtime.h>
#include <hip/hip_bf16.h>
#include <math.h>

#define N_NODES 50000
#define N_EDGES 800000
#define EMB 128
#define LH 256
#define NSENT 2048
#define MAXLEN 32
#define SCAN_NB 196   // ceil(50000/256)
#define NG 64         // sentences per group
#define NGRP 32       // groups (NSENT/NG)

typedef __attribute__((ext_vector_type(8))) short short8;
typedef __attribute__((ext_vector_type(4))) float f32x4;

__device__ __forceinline__ unsigned short f2bf_u(float f) {
    __hip_bfloat16 h = __float2bfloat16(f);
    return *reinterpret_cast<unsigned short*>(&h);
}
__device__ __forceinline__ float bfu2f(unsigned short u) {
    unsigned int x = ((unsigned int)u) << 16;
    return __uint_as_float(x);
}

// fast activations: ~1e-7 abs error, negligible vs bf16 h-state rounding (2^-9)
__device__ __forceinline__ float fsig(float x) {
    return 1.f / (1.f + __expf(-x));
}
__device__ __forceinline__ float ftanh(float x) {
    return 1.f - 2.f / (__expf(2.f * x) + 1.f);
}

#define WAITVM0() __builtin_amdgcn_s_waitcnt(0xF70)   // vmcnt(0)

// async global->LDS, 16B/lane; gsrc per-lane, LDS dst = wave-uniform base + lane*16
__device__ __forceinline__ void gload_lds16(const void* gsrc, void* ldst) {
    __builtin_amdgcn_global_load_lds(
        (const __attribute__((address_space(1))) unsigned int*)gsrc,
        (__attribute__((address_space(3))) unsigned int*)ldst, 16, 0, 0);
}

// ---------------- CSR build ----------------

__global__ void k_hist(const int* __restrict__ dst, int* __restrict__ cnt) {
    int i = blockIdx.x * 256 + threadIdx.x;
    if (i < N_EDGES) atomicAdd(&cnt[dst[i]], 1);
}

__global__ void k_scan_blk(const int* __restrict__ cnt, int* __restrict__ row_ptr,
                           int* __restrict__ blk) {
    int b = blockIdx.x, t = threadIdx.x;
    int i = b * 256 + t;
    int lane = t & 63, wid = t >> 6;
    int v = (i < N_NODES) ? cnt[i] : 0;
    int x = v;
    #pragma unroll
    for (int off = 1; off < 64; off <<= 1) {
        int y = __shfl_up(x, off);
        if (lane >= off) x += y;
    }
    __shared__ int ws[4];
    if (lane == 63) ws[wid] = x;
    __syncthreads();
    if (t == 0) {
        int s = 0;
        #pragma unroll
        for (int j = 0; j < 4; j++) { int tmp = ws[j]; ws[j] = s; s += tmp; }
        blk[b] = s;
    }
    __syncthreads();
    if (i < N_NODES) row_ptr[i] = ws[wid] + x - v;
}

__global__ void k_scan_tot(int* __restrict__ blk) {
    int t = threadIdx.x;
    int lane = t & 63, wid = t >> 6;
    int v = (t < SCAN_NB) ? blk[t] : 0;
    int x = v;
    #pragma unroll
    for (int off = 1; off < 64; off <<= 1) {
        int y = __shfl_up(x, off);
        if (lane >= off) x += y;
    }
    __shared__ int ws[4];
    if (lane == 63) ws[wid] = x;
    __syncthreads();
    if (t == 0) {
        int s = 0;
        #pragma unroll
        for (int j = 0; j < 4; j++) { int tmp = ws[j]; ws[j] = s; s += tmp; }
    }
    __syncthreads();
    if (t < SCAN_NB) blk[t] = ws[wid] + x - v;
}

// + folded cnt reset (safe: runs after k_scan_blk's last read of cnt)
__global__ void k_scan_add(int* __restrict__ row_ptr, const int* __restrict__ blk,
                           int* __restrict__ cnt) {
    int i = blockIdx.x * 256 + threadIdx.x;
    if (i < N_NODES) {
        row_ptr[i] += blk[i >> 8];
        cnt[i] = 0;
    }
    if (i == 0) row_ptr[N_NODES] = N_EDGES;
}

__global__ void k_scatter(const int* __restrict__ src, const int* __restrict__ dst,
                          const int* __restrict__ row_ptr, int* __restrict__ cnt,
                          int* __restrict__ edge_src) {
    int i = blockIdx.x * 256 + threadIdx.x;
    if (i < N_EDGES) {
        int d = dst[i];
        int pos = row_ptr[d] + atomicAdd(&cnt[d], 1);
        edge_src[pos] = src[i];
    }
}

// ---------------- aggregation: wave per node, 2-deep gather pipeline ----------------

__global__ void k_aggregate_bf(const unsigned short* __restrict__ feat,
                               const int* __restrict__ row_ptr,
                               const int* __restrict__ edge_src,
                               unsigned short* __restrict__ outb) {
    int w = (blockIdx.x * 256 + threadIdx.x) >> 6;
    int lane = threadIdx.x & 63;
    if (w >= N_NODES) return;
    int slot = lane >> 4, li = lane & 15;
    int beg = row_ptr[w], end = row_ptr[w + 1];
    float acc[8] = {};
    short8 vA = {}, vB = {};
    {
        int eA = beg + slot, eB = beg + 4 + slot;
        int sA = (eA < end) ? edge_src[eA] : -1;
        int sB = (eB < end) ? edge_src[eB] : -1;
        if (sA >= 0) vA = *(const short8*)((const short*)feat + (size_t)sA * EMB + li * 8);
        if (sB >= 0) vB = *(const short8*)((const short*)feat + (size_t)sB * EMB + li * 8);
    }
    #pragma unroll 1
    for (int e = beg; e < end; e += 8) {
        int eA2 = e + 8 + slot, eB2 = e + 12 + slot;
        int sA2 = (eA2 < end) ? edge_src[eA2] : -1;
        int sB2 = (eB2 < end) ? edge_src[eB2] : -1;
        short8 vA2 = {}, vB2 = {};
        if (sA2 >= 0) vA2 = *(const short8*)((const short*)feat + (size_t)sA2 * EMB + li * 8);
        if (sB2 >= 0) vB2 = *(const short8*)((const short*)feat + (size_t)sB2 * EMB + li * 8);
        if (e + slot < end) {
            #pragma unroll
            for (int j = 0; j < 8; j++) acc[j] += bfu2f((unsigned short)vA[j]);
        }
        if (e + 4 + slot < end) {
            #pragma unroll
            for (int j = 0; j < 8; j++) acc[j] += bfu2f((unsigned short)vB[j]);
        }
        vA = vA2; vB = vB2;
    }
    #pragma unroll
    for (int j = 0; j < 8; j++) {
        float t = acc[j];
        t += __shfl_xor(t, 16);
        t += __shfl_xor(t, 32);
        acc[j] = t;
    }
    if (slot == 0) {
        short8 o;
        #pragma unroll
        for (int j = 0; j < 8; j++) o[j] = (short)f2bf_u(acc[j]);
        *(short8*)((short*)outb + (size_t)w * EMB + li * 8) = o;
    }
}

// ---------------- GCN linear via MFMA ----------------

__global__ void __launch_bounds__(256)
k_gcn_mfma(const unsigned short* __restrict__ Ab,   // [M][128] bf16
           const unsigned short* __restrict__ Wb,   // [128][128] bf16
           const float* __restrict__ bias,
           unsigned short* __restrict__ outb,
           int M, int do_tanh) {
    int tid = threadIdx.x;
    int w = tid >> 6, lane = tid & 63;
    int l16 = lane & 15, quad = lane >> 4;
    int rbase = blockIdx.x * 64 + w * 16;
    int arow = rbase + l16;
    if (arow >= M) arow = M - 1;
    const short* Ap = (const short*)Ab + (size_t)arow * 128 + quad * 8;
    const short* Wp = (const short*)Wb;
    f32x4 acc[8] = {};
    #pragma unroll
    for (int ks = 0; ks < 4; ks++) {
        short8 a = *(const short8*)(Ap + ks * 32);
        #pragma unroll
        for (int ct = 0; ct < 8; ct++) {
            short8 b = *(const short8*)(Wp + (size_t)(ct * 16 + l16) * 128 + ks * 32 + quad * 8);
            acc[ct] = __builtin_amdgcn_mfma_f32_16x16x32_bf16(a, b, acc[ct], 0, 0, 0);
        }
    }
    #pragma unroll
    for (int ct = 0; ct < 8; ct++) {
        float bcol = bias[ct * 16 + l16];
        #pragma unroll
        for (int r = 0; r < 4; r++) {
            int row = rbase + quad * 4 + r;
            if (row < M) {
                float v = acc[ct][r] + bcol;
                if (do_tanh) v = tanhf(v);
                outb[(size_t)row * 128 + ct * 16 + l16] = f2bf_u(v);
            }
        }
    }
}

// ---------------- prep: Wpk3 + bsum + W1b/W2b + tobf16 + buffer zeroing -------------
// R25: dispatch consolidation -- all independent first-stage writes fused into one
// grid (was: prep + tobf16 + 3 memsets = 5 dispatches; now 1). Ranges:
//   [0, 393216)                Wpk3 packing (per-u-slice fragment-linear Wi|Wh)
//   [..., +1024)               bsum = bi + bh
//   [..., +16384)              W1b bf16
//   [..., +16384)              W2b bf16
//   [..., +1600000)            inputs fp32 -> in_bf bf16 (float4 granules)
//   [..., +262144)             hX zero (ULL)
//   [..., +1024)               gcnt zero
//   [..., +50000)              cnt zero (for k_hist)

#define PR0 (1024 * 384)
#define PR1 (PR0 + 1024)
#define PR2 (PR1 + 16384)
#define PR3 (PR2 + 16384)
#define PR4 (PR3 + N_NODES * EMB / 4)
#define PR5 (PR4 + 2 * NSENT * 64)
#define PR6 (PR5 + NGRP * 32)
#define PR7 (PR6 + N_NODES)

__global__ void k_prep(const float* __restrict__ Wi, const float* __restrict__ Wh,
                       const float* __restrict__ bi, const float* __restrict__ bh,
                       const float* __restrict__ W1, const float* __restrict__ W2,
                       const float* __restrict__ inputs,
                       unsigned short* __restrict__ Wpk3, float* __restrict__ bsum,
                       unsigned short* __restrict__ W1b, unsigned short* __restrict__ W2b,
                       unsigned short* __restrict__ in_bf,
                       unsigned long long* __restrict__ hX,
                       int* __restrict__ gcnt, int* __restrict__ cnt) {
    int idx = blockIdx.x * 256 + threadIdx.x;
    if (idx < PR0) {
        int R = idx / 384, k = idx - R * 384;
        float v = (k < 128) ? Wi[R * 128 + k] : Wh[R * 256 + (k - 128)];
        int g = R >> 8, u = R & 255;
        int usl = u >> 5, up = u & 31;
        int ct = g * 2 + (up >> 4);
        int l16v = up & 15;
        int ks = k >> 5, kk = k & 31;
        int quad = kk >> 3, jj = kk & 7;
        int lane = quad * 16 + l16v;
        Wpk3[(((size_t)usl * 12 + ks) * 8 + ct) * 512 + lane * 8 + jj] = f2bf_u(v);
    } else if (idx < PR1) {
        int r = idx - PR0;
        bsum[r] = bi[r] + bh[r];
    } else if (idx < PR2) {
        int r = idx - PR1;
        W1b[r] = f2bf_u(W1[r]);
    } else if (idx < PR3) {
        int r = idx - PR2;
        W2b[r] = f2bf_u(W2[r]);
    } else if (idx < PR4) {
        int i = idx - PR3;
        float4 v = ((const float4*)inputs)[i];
        ushort4 u4;
        u4.x = f2bf_u(v.x); u4.y = f2bf_u(v.y); u4.z = f2bf_u(v.z); u4.w = f2bf_u(v.w);
        ((ushort4*)in_bf)[i] = u4;
    } else if (idx < PR5) {
        hX[idx - PR4] = 0ull;
    } else if (idx < PR6) {
        gcnt[idx - PR5] = 0;
    } else if (idx < PR7) {
        cnt[idx - PR6] = 0;
    }
}

// ---------------- LSTM: weight-stationary, R11 sync, hv under xb-writes --------------
// R25 LSTM delta vs R11 (192us): after Bspin (now unconditional -- it guarantees all
// waves passed the x-GEMM), issue the hv coherence-point loads FIRST, then the
// xb(t+1) ds_writes (depend only on long-arrived xr -> vmcnt(8), not 0), then hb
// writes consume hv -> ~200cyc of the ~700cyc hv RT hidden, and xb-writes leave the
// tail (shorter store-ACK chain). Barriers/step unchanged (Bspin, Bh, B3, Bx).
// WAR audit: xb write(t) after Bspin(t), read at x-GEMM(t+1) after Bx(t); hb write(t)
// vs h-GEMM(t-1) reads separated by B3+Bx+Bspin; gl write(t) vs pointwise(t-1) reads
// separated by Bx+Bspin+Bh.

__global__ void __launch_bounds__(512)
__attribute__((amdgpu_waves_per_eu(2, 2)))
k_lstm_ws8(const unsigned short* __restrict__ hn_bf,   // [N_NODES][128] bf16
           const unsigned short* __restrict__ Wpk3,    // packed, see k_prep
           const float* __restrict__ bsum,             // [1024]
           const int* __restrict__ sidx,               // [NSENT][MAXLEN]
           const int* __restrict__ lengths,            // [NSENT]
           unsigned long long* __restrict__ hX,        // [2][NSENT][64] (256 bf16/row)
           int* __restrict__ gcnt,                     // [NGRP*32] arrival ctrs (zeroed)
           float* __restrict__ h_last) {               // [NSENT][256] fp32
    __shared__ unsigned short xb[64 * 128];            // 16 KB x_t (chunk-swizzled)
    __shared__ unsigned short hb[64 * 256];            // 32 KB h_t (chunk-swizzled)
    __shared__ float gl[64 * 132];                     // 33 KB gates (independent region)
    __shared__ int nid_sh[NG * 33];                    // 8448 B

    int tid = threadIdx.x;
    int w = tid >> 6, lane = tid & 63;
    int l16 = lane & 15, quad = lane >> 4;
    int usl = blockIdx.x >> 5;        // u-slice 0..7
    int grp = blockIdx.x & 31;        // sentence group 0..31 (same-XCD under %8 rr)
    int s0 = grp * NG;
    const short* hnp = (const short*)hn_bf;

    int m2 = w >> 2, cp4 = w & 3;     // GEMM wave grid: 2 m-groups x 4 col-groups (32x32)
    int row0 = m2 * 32 + l16, row1 = row0 + 16;

    // ---- prologue: this wave's 24 B-fragments -> REGISTERS (time-invariant) ----
    short8 breg[12][2];
    {
        const short* wsrc = (const short*)Wpk3 + (size_t)usl * 49152 + lane * 8;
        #pragma unroll
        for (int ks = 0; ks < 12; ks++)
            #pragma unroll
            for (int c = 0; c < 2; c++)
                breg[ks][c] = *(const short8*)(wsrc + (size_t)(ks * 8 + cp4 * 2 + c) * 512);
    }
    // bias for this wave's two 16-col tiles (folded into acc init each step)
    float bc0 = bsum[cp4 * 256 + usl * 32 + l16];
    float bc1 = bsum[cp4 * 256 + usl * 32 + 16 + l16];

    // x0 -> xb via async gload (pre-swizzled source)
    #pragma unroll
    for (int i = 0; i < 2; i++) {
        int row = w * 8 + i * 4 + quad;
        int nid = sidx[(size_t)(s0 + row) * MAXLEN + 0];
        int schunk = (l16 & ~7) | ((l16 ^ row) & 7);
        gload_lds16(hnp + (size_t)nid * 128 + schunk * 8,
                    (void*)((char*)xb + (size_t)(w * 8 + i * 4) * 256));
    }
    for (int i = tid; i < NG * 32; i += 512)
        nid_sh[(i >> 5) * 33 + (i & 31)] = sidx[(size_t)(s0 + (i >> 5)) * MAXLEN + (i & 31)];
    for (int i = tid; i < 64 * 128; i += 512) ((unsigned int*)hb)[i] = 0;  // h_{-1}=0

    // pointwise-thread constants: (psent = tid>>3, 4 h-cols u'0 = (tid&7)*4 ..)
    int psent = tid >> 3, j8 = tid & 7, u0 = j8 * 4;
    int len_reg = lengths[s0 + psent];
    float c_reg[4] = {};

    short8 xr[2];                     // x(t+1) register prefetch

    __syncthreads();                  // prologue staged (drains gload vmcnt)

    #pragma unroll 1
    for (int t = 0; t < MAXLEN; t++) {
        // ---- issue x(t+1) global->reg prefetch ----
        if (t + 1 < MAXLEN) {
            int row = tid >> 3;
            int nid = nid_sh[row * 33 + (t + 1)];
            #pragma unroll
            for (int k = 0; k < 2; k++) {
                int slot = j8 * 2 + k;
                int c = (slot & ~7) | ((slot ^ row) & 7);
                xr[k] = *(const short8*)(hnp + (size_t)nid * 128 + c * 8);
            }
        }

        // ---- x-part GEMM: ks 0..3 (xb only) -- runs BEFORE the spin ----
        f32x4 acc00 = {bc0, bc0, bc0, bc0};
        f32x4 acc01 = {bc1, bc1, bc1, bc1};
        f32x4 acc10 = {bc0, bc0, bc0, bc0};
        f32x4 acc11 = {bc1, bc1, bc1, bc1};
        #pragma unroll
        for (int ks = 0; ks < 4; ks++) {
            int kc = ks * 4 + quad;
            short8 a0 = *(const short8*)(xb + row0 * 128 + (((kc & ~7) | ((kc ^ row0) & 7)) * 8));
            short8 a1 = *(const short8*)(xb + row1 * 128 + (((kc & ~7) | ((kc ^ row1) & 7)) * 8));
            acc00 = __builtin_amdgcn_mfma_f32_16x16x32_bf16(a0, breg[ks][0], acc00, 0, 0, 0);
            acc01 = __builtin_amdgcn_mfma_f32_16x16x32_bf16(a0, breg[ks][1], acc01, 0, 0, 0);
            acc10 = __builtin_amdgcn_mfma_f32_16x16x32_bf16(a1, breg[ks][0], acc10, 0, 0, 0);
            acc11 = __builtin_amdgcn_mfma_f32_16x16x32_bf16(a1, breg[ks][1], acc11, 0, 0, 0);
        }

        // ---- spin (publish->observe hidden under x-part) ----
        if (t > 0 && tid == 0) {
            while (__hip_atomic_load(&gcnt[grp * 32], __ATOMIC_RELAXED,
                                     __HIP_MEMORY_SCOPE_AGENT) < 8 * t)
                __builtin_amdgcn_s_sleep(1);
        }
        __syncthreads();   // Bspin: broadcast; also proves all waves passed x-GEMM

        // ---- issue h_t coherence-point loads FIRST (RT hidden under xb writes) ----
        unsigned long long hv[8];
        if (t > 0) {
            const unsigned long long* hr = hX + (size_t)(t & 1) * NSENT * 64
                                           + (size_t)(s0 + psent) * 64 + j8 * 8;
            #pragma unroll
            for (int k = 0; k < 8; k++)
                hv[k] = __hip_atomic_load(&hr[k], __ATOMIC_RELAXED,
                                          __HIP_MEMORY_SCOPE_AGENT);
        }

        // ---- xb(t+1) ds_writes (wait xr only: vmcnt(8), hv still in flight) ----
        if (t + 1 < MAXLEN) {
            int row = tid >> 3;
            #pragma unroll
            for (int k = 0; k < 2; k++) {
                int slot = j8 * 2 + k;
                *(short8*)(xb + row * 128 + slot * 8) = xr[k];
            }
        }

        // ---- h_t -> hb (consumes hv) ----
        if (t > 0) {
            #pragma unroll
            for (int p = 0; p < 4; p++) {
                int cc = j8 * 4 + p;
                int slot = (cc & ~7) | ((cc ^ psent) & 7);
                union { unsigned long long q[2]; short8 s; } uu;
                uu.q[0] = hv[2 * p]; uu.q[1] = hv[2 * p + 1];
                *(short8*)(hb + psent * 256 + slot * 8) = uu.s;
            }
        }
        __syncthreads();   // Bh: xb(t+1)/hb(t) visible to all waves

        // ---- h-part GEMM: ks 4..11 (hb) ----
        #pragma unroll
        for (int ks = 4; ks < 12; ks++) {
            int kc = (ks - 4) * 4 + quad;
            short8 a0 = *(const short8*)(hb + row0 * 256 + (((kc & ~7) | ((kc ^ row0) & 7)) * 8));
            short8 a1 = *(const short8*)(hb + row1 * 256 + (((kc & ~7) | ((kc ^ row1) & 7)) * 8));
            acc00 = __builtin_amdgcn_mfma_f32_16x16x32_bf16(a0, breg[ks][0], acc00, 0, 0, 0);
            acc01 = __builtin_amdgcn_mfma_f32_16x16x32_bf16(a0, breg[ks][1], acc01, 0, 0, 0);
            acc10 = __builtin_amdgcn_mfma_f32_16x16x32_bf16(a1, breg[ks][0], acc10, 0, 0, 0);
            acc11 = __builtin_amdgcn_mfma_f32_16x16x32_bf16(a1, breg[ks][1], acc11, 0, 0, 0);
        }

        // ---- acc (pre-biased) -> gates f32 [64][132] (ncol = g*32+u', g = cp4) ----
        #pragma unroll
        for (int r = 0; r < 4; r++) {
            int se0 = m2 * 32 + quad * 4 + r;
            int se1 = se0 + 16;
            gl[se0 * 132 + cp4 * 32 + l16]      = acc00[r];
            gl[se0 * 132 + cp4 * 32 + 16 + l16] = acc01[r];
            gl[se1 * 132 + cp4 * 32 + l16]      = acc10[r];
            gl[se1 * 132 + cp4 * 32 + 16 + l16] = acc11[r];
        }
        __syncthreads();   // B3: gates ready

        // ---- pointwise c/h for (psent, u-cols usl*32+u0 .. +3) ----
        {
            float4 G[4];
            #pragma unroll
            for (int g = 0; g < 4; g++)
                G[g] = *(const float4*)&gl[psent * 132 + g * 32 + u0];
            float hv4[4];
            const float* Gp0 = (const float*)&G[0];
            const float* Gp1 = (const float*)&G[1];
            const float* Gp2 = (const float*)&G[2];
            const float* Gp3 = (const float*)&G[3];
            #pragma unroll
            for (int j = 0; j < 4; j++) {
                float i_ = fsig(Gp0[j]);
                float f_ = fsig(Gp1[j]);
                float g_ = ftanh(Gp2[j]);
                float o_ = fsig(Gp3[j]);
                float c = f_ * c_reg[j] + i_ * g_;
                c_reg[j] = c;
                hv4[j] = o_ * ftanh(c);
            }
            unsigned long long hq =
                  (unsigned long long)f2bf_u(hv4[0])
                | ((unsigned long long)f2bf_u(hv4[1]) << 16)
                | ((unsigned long long)f2bf_u(hv4[2]) << 32)
                | ((unsigned long long)f2bf_u(hv4[3]) << 48);
            unsigned long long* hw = hX + (size_t)((t + 1) & 1) * NSENT * 64
                                     + (size_t)(s0 + psent) * 64 + usl * 8 + j8;
            __hip_atomic_store(hw, hq, __ATOMIC_RELAXED, __HIP_MEMORY_SCOPE_AGENT);
            if (len_reg == t + 1) {
                float4 o4 = make_float4(hv4[0], hv4[1], hv4[2], hv4[3]);
                *(float4*)&h_last[(size_t)(s0 + psent) * 256 + usl * 32 + u0] = o4;
            }
        }

        // ---- tail: ACK hX stores, arrive ----
        if (t + 1 < MAXLEN) {
            WAITVM0();         // hX stores ACK'd at coherence point
            __syncthreads();   // Bx: joins all waves' ACKs
            if (tid == 0)
                __hip_atomic_fetch_add(&gcnt[grp * 32], 1, __ATOMIC_RELAXED,
                                       __HIP_MEMORY_SCOPE_AGENT);
        }
    }
}

// ---------------- classifier ----------------

__global__ void k_classifier(const float* __restrict__ h_last,
                             const float* __restrict__ Wc1, const float* __restrict__ bc1,
                             const float* __restrict__ Wc2, const float* __restrict__ bc2,
                             float* __restrict__ out) {
    int lane = threadIdx.x & 63;
    int wslot = threadIdx.x >> 6;
    int s = blockIdx.x * 4 + wslot;
    __shared__ float e_sh[4][256];
    const float* hr = h_last + (size_t)s * 256;
    #pragma unroll
    for (int i = 0; i < 4; i++) {
        float v = hr[lane + 64 * i];
        e_sh[wslot][lane + 64 * i] = fmaxf(v, 0.f);
    }
    __syncthreads();
    float zpart = 0.f;
    #pragma unroll
    for (int jj = 0; jj < 2; jj++) {
        int j = lane + 64 * jj;
        float a = bc1[j];
        const float4* wr = (const float4*)(Wc1 + (size_t)j * 256);
        #pragma unroll 8
        for (int k4 = 0; k4 < 64; k4++) {
            float4 wv = wr[k4];
            float4 e = *(const float4*)&e_sh[wslot][k4 * 4];
            a += wv.x * e.x + wv.y * e.y + wv.z * e.z + wv.w * e.w;
        }
        a = fmaxf(a, 0.f);
        zpart += a * Wc2[j];
    }
    #pragma unroll
    for (int off = 32; off > 0; off >>= 1) zpart += __shfl_down(zpart, off);
    if (lane == 0) out[s] = zpart + bc2[0];
}

// ---------------- launcher (12 dispatches, 0 memsets) ----------------

extern "C" void kernel_launch(void* const* d_in, const int* in_sizes, int n_in,
                              void* d_out, int out_size, void* d_ws, size_t ws_size,
                              hipStream_t stream) {
    const float* inputs = (const float*)d_in[0];
    const float* W1  = (const float*)d_in[1];
    const float* b1  = (const float*)d_in[2];
    const float* W2  = (const float*)d_in[3];
    const float* b2  = (const float*)d_in[4];
    const float* Wi  = (const float*)d_in[5];
    const float* Wh  = (const float*)d_in[6];
    const float* bi  = (const float*)d_in[7];
    const float* bh  = (const float*)d_in[8];
    const float* Wc1 = (const float*)d_in[9];
    const float* bc1 = (const float*)d_in[10];
    const float* Wc2 = (const float*)d_in[11];
    const float* bc2 = (const float*)d_in[12];
    const int* src      = (const int*)d_in[13];
    const int* dst      = (const int*)d_in[14];
    const int* sidx     = (const int*)d_in[15];
    const int* lengths  = (const int*)d_in[16];
    float* out = (float*)d_out;

    char* ws = (char*)d_ws;
    size_t off = 0;
    auto alloc = [&](size_t bytes) -> void* {
        void* p = ws + off;
        off = (off + bytes + 255) & ~(size_t)255;
        return p;
    };
    unsigned short* in_bf  = (unsigned short*)alloc(2 * (size_t)N_NODES * EMB);
    unsigned short* agg_bf = (unsigned short*)alloc(2 * (size_t)N_NODES * EMB);
    unsigned short* h_bf   = (unsigned short*)alloc(2 * (size_t)N_NODES * EMB);
    unsigned short* hn_bf  = (unsigned short*)alloc(2 * (size_t)N_NODES * EMB);
    int*   row_ptr  = (int*)alloc(sizeof(int) * (N_NODES + 1));
    int*   cnt      = (int*)alloc(sizeof(int) * N_NODES);
    int*   blk      = (int*)alloc(sizeof(int) * SCAN_NB);
    int*   edge_src = (int*)alloc(sizeof(int) * N_EDGES);
    unsigned short* Wpk3 = (unsigned short*)alloc(2 * 8 * 12 * 8 * 512);  // 768 KB
    unsigned short* W1b  = (unsigned short*)alloc(2 * 128 * 128);
    unsigned short* W2b  = (unsigned short*)alloc(2 * 128 * 128);
    float* bsum     = (float*)alloc(sizeof(float) * 1024);
    float* hlast    = (float*)alloc(sizeof(float) * NSENT * LH);
    unsigned long long* hX = (unsigned long long*)alloc(2 * (size_t)NSENT * 64 * 8);  // 2 MB
    int* gcnt       = (int*)alloc(sizeof(int) * NGRP * 32);

    // fused prep: weights pack + bf16 converts + all buffer zeroing
    k_prep<<<(PR7 + 255) / 256, 256, 0, stream>>>(
        Wi, Wh, bi, bh, W1, W2, inputs, Wpk3, bsum, W1b, W2b, in_bf, hX, gcnt, cnt);

    // CSR build (cnt zeroed by k_prep; re-zeroed for scatter inside k_scan_add)
    k_hist<<<(N_EDGES + 255) / 256, 256, 0, stream>>>(dst, cnt);
    k_scan_blk<<<SCAN_NB, 256, 0, stream>>>(cnt, row_ptr, blk);
    k_scan_tot<<<1, 256, 0, stream>>>(blk);
    k_scan_add<<<SCAN_NB, 256, 0, stream>>>(row_ptr, blk, cnt);
    k_scatter<<<(N_EDGES + 255) / 256, 256, 0, stream>>>(src, dst, row_ptr, cnt, edge_src);

    // GCN (bf16 path)
    k_aggregate_bf<<<(N_NODES * 64) / 256, 256, 0, stream>>>(in_bf, row_ptr, edge_src, agg_bf);
    k_gcn_mfma<<<(N_NODES + 63) / 64, 256, 0, stream>>>(agg_bf, W1b, b1, h_bf, N_NODES, 1);
    k_aggregate_bf<<<(N_NODES * 64) / 256, 256, 0, stream>>>(h_bf, row_ptr, edge_src, agg_bf);
    k_gcn_mfma<<<(N_NODES + 63) / 64, 256, 0, stream>>>(agg_bf, W2b, b2, hn_bf, N_NODES, 0);

    // LSTM: weight-stationary (B in VGPRs), R11 sync, hv-under-xb-writes
    k_lstm_ws8<<<NGRP * 8, 512, 0, stream>>>(hn_bf, Wpk3, bsum, sidx, lengths,
                                             hX, gcnt, hlast);

    // classifier
    k_classifier<<<NSENT / 4, 256, 0, stream>>>(hlast, Wc1, bc1, Wc2, bc2, out);
}

// Round 13
// 470.006 us; speedup vs baseline: 1.1656x; 1.0708x over previous
//
#include <hip/hip_runtime.h>
#include <hip/hip_bf16.h>
#include <math.h>

#define N_NODES 50000
#define N_EDGES 800000
#define EMB 128
#define LH 256
#define NSENT 2048
#define MAXLEN 32
#define SCAN_NB 196   // ceil(50000/256)
#define NG 64         // sentences per group
#define NGRP 32       // groups (NSENT/NG)

typedef __attribute__((ext_vector_type(8))) short short8;
typedef __attribute__((ext_vector_type(4))) float f32x4;
typedef __attribute__((ext_vector_type(4))) unsigned int u32x4;
typedef __attribute__((ext_vector_type(2))) unsigned int u32x2;

__device__ __forceinline__ unsigned short f2bf_u(float f) {
    __hip_bfloat16 h = __float2bfloat16(f);
    return *reinterpret_cast<unsigned short*>(&h);
}
__device__ __forceinline__ float bfu2f(unsigned short u) {
    unsigned int x = ((unsigned int)u) << 16;
    return __uint_as_float(x);
}

// fast activations: ~1e-7 abs error, negligible vs bf16 h-state rounding (2^-9)
__device__ __forceinline__ float fsig(float x) {
    return 1.f / (1.f + __expf(-x));
}
__device__ __forceinline__ float ftanh(float x) {
    return 1.f - 2.f / (__expf(2.f * x) + 1.f);
}

#define WAITVM0() __builtin_amdgcn_s_waitcnt(0xF70)   // vmcnt(0)

// device-coherent wide access: sc0 sc1 = bypass L1/L2, served at the device
// coherence point (same rendezvous as agent-scope atomics) but wave-coalescable.
__device__ __forceinline__ u32x4 dc_load16(const void* p) {
    u32x4 r;
    asm volatile("global_load_dwordx4 %0, %1, off sc0 sc1"
                 : "=v"(r) : "v"(p) : "memory");
    return r;
}
__device__ __forceinline__ void dc_store8(void* p, u32x2 v) {
    asm volatile("global_store_dwordx2 %0, %1, off sc0 sc1"
                 :: "v"(p), "v"(v) : "memory");
}

// async global->LDS, 16B/lane; gsrc per-lane, LDS dst = wave-uniform base + lane*16
__device__ __forceinline__ void gload_lds16(const void* gsrc, void* ldst) {
    __builtin_amdgcn_global_load_lds(
        (const __attribute__((address_space(1))) unsigned int*)gsrc,
        (__attribute__((address_space(3))) unsigned int*)ldst, 16, 0, 0);
}

// ---------------- CSR build ----------------

__global__ void k_hist(const int* __restrict__ dst, int* __restrict__ cnt) {
    int i = blockIdx.x * 256 + threadIdx.x;
    if (i < N_EDGES) atomicAdd(&cnt[dst[i]], 1);
}

__global__ void k_scan_blk(const int* __restrict__ cnt, int* __restrict__ row_ptr,
                           int* __restrict__ blk) {
    int b = blockIdx.x, t = threadIdx.x;
    int i = b * 256 + t;
    int lane = t & 63, wid = t >> 6;
    int v = (i < N_NODES) ? cnt[i] : 0;
    int x = v;
    #pragma unroll
    for (int off = 1; off < 64; off <<= 1) {
        int y = __shfl_up(x, off);
        if (lane >= off) x += y;
    }
    __shared__ int ws[4];
    if (lane == 63) ws[wid] = x;
    __syncthreads();
    if (t == 0) {
        int s = 0;
        #pragma unroll
        for (int j = 0; j < 4; j++) { int tmp = ws[j]; ws[j] = s; s += tmp; }
        blk[b] = s;
    }
    __syncthreads();
    if (i < N_NODES) row_ptr[i] = ws[wid] + x - v;
}

__global__ void k_scan_tot(int* __restrict__ blk) {
    int t = threadIdx.x;
    int lane = t & 63, wid = t >> 6;
    int v = (t < SCAN_NB) ? blk[t] : 0;
    int x = v;
    #pragma unroll
    for (int off = 1; off < 64; off <<= 1) {
        int y = __shfl_up(x, off);
        if (lane >= off) x += y;
    }
    __shared__ int ws[4];
    if (lane == 63) ws[wid] = x;
    __syncthreads();
    if (t == 0) {
        int s = 0;
        #pragma unroll
        for (int j = 0; j < 4; j++) { int tmp = ws[j]; ws[j] = s; s += tmp; }
    }
    __syncthreads();
    if (t < SCAN_NB) blk[t] = ws[wid] + x - v;
}

// + folded cnt reset (safe: runs after k_scan_blk's last read of cnt)
__global__ void k_scan_add(int* __restrict__ row_ptr, const int* __restrict__ blk,
                           int* __restrict__ cnt) {
    int i = blockIdx.x * 256 + threadIdx.x;
    if (i < N_NODES) {
        row_ptr[i] += blk[i >> 8];
        cnt[i] = 0;
    }
    if (i == 0) row_ptr[N_NODES] = N_EDGES;
}

__global__ void k_scatter(const int* __restrict__ src, const int* __restrict__ dst,
                          const int* __restrict__ row_ptr, int* __restrict__ cnt,
                          int* __restrict__ edge_src) {
    int i = blockIdx.x * 256 + threadIdx.x;
    if (i < N_EDGES) {
        int d = dst[i];
        int pos = row_ptr[d] + atomicAdd(&cnt[d], 1);
        edge_src[pos] = src[i];
    }
}

// ---------------- aggregation: wave per node, 2-deep gather pipeline ----------------

__global__ void k_aggregate_bf(const unsigned short* __restrict__ feat,
                               const int* __restrict__ row_ptr,
                               const int* __restrict__ edge_src,
                               unsigned short* __restrict__ outb) {
    int w = (blockIdx.x * 256 + threadIdx.x) >> 6;
    int lane = threadIdx.x & 63;
    if (w >= N_NODES) return;
    int slot = lane >> 4, li = lane & 15;
    int beg = row_ptr[w], end = row_ptr[w + 1];
    float acc[8] = {};
    short8 vA = {}, vB = {};
    {
        int eA = beg + slot, eB = beg + 4 + slot;
        int sA = (eA < end) ? edge_src[eA] : -1;
        int sB = (eB < end) ? edge_src[eB] : -1;
        if (sA >= 0) vA = *(const short8*)((const short*)feat + (size_t)sA * EMB + li * 8);
        if (sB >= 0) vB = *(const short8*)((const short*)feat + (size_t)sB * EMB + li * 8);
    }
    #pragma unroll 1
    for (int e = beg; e < end; e += 8) {
        int eA2 = e + 8 + slot, eB2 = e + 12 + slot;
        int sA2 = (eA2 < end) ? edge_src[eA2] : -1;
        int sB2 = (eB2 < end) ? edge_src[eB2] : -1;
        short8 vA2 = {}, vB2 = {};
        if (sA2 >= 0) vA2 = *(const short8*)((const short*)feat + (size_t)sA2 * EMB + li * 8);
        if (sB2 >= 0) vB2 = *(const short8*)((const short*)feat + (size_t)sB2 * EMB + li * 8);
        if (e + slot < end) {
            #pragma unroll
            for (int j = 0; j < 8; j++) acc[j] += bfu2f((unsigned short)vA[j]);
        }
        if (e + 4 + slot < end) {
            #pragma unroll
            for (int j = 0; j < 8; j++) acc[j] += bfu2f((unsigned short)vB[j]);
        }
        vA = vA2; vB = vB2;
    }
    #pragma unroll
    for (int j = 0; j < 8; j++) {
        float t = acc[j];
        t += __shfl_xor(t, 16);
        t += __shfl_xor(t, 32);
        acc[j] = t;
    }
    if (slot == 0) {
        short8 o;
        #pragma unroll
        for (int j = 0; j < 8; j++) o[j] = (short)f2bf_u(acc[j]);
        *(short8*)((short*)outb + (size_t)w * EMB + li * 8) = o;
    }
}

// ---------------- GCN linear via MFMA ----------------

__global__ void __launch_bounds__(256)
k_gcn_mfma(const unsigned short* __restrict__ Ab,   // [M][128] bf16
           const unsigned short* __restrict__ Wb,   // [128][128] bf16
           const float* __restrict__ bias,
           unsigned short* __restrict__ outb,
           int M, int do_tanh) {
    int tid = threadIdx.x;
    int w = tid >> 6, lane = tid & 63;
    int l16 = lane & 15, quad = lane >> 4;
    int rbase = blockIdx.x * 64 + w * 16;
    int arow = rbase + l16;
    if (arow >= M) arow = M - 1;
    const short* Ap = (const short*)Ab + (size_t)arow * 128 + quad * 8;
    const short* Wp = (const short*)Wb;
    f32x4 acc[8] = {};
    #pragma unroll
    for (int ks = 0; ks < 4; ks++) {
        short8 a = *(const short8*)(Ap + ks * 32);
        #pragma unroll
        for (int ct = 0; ct < 8; ct++) {
            short8 b = *(const short8*)(Wp + (size_t)(ct * 16 + l16) * 128 + ks * 32 + quad * 8);
            acc[ct] = __builtin_amdgcn_mfma_f32_16x16x32_bf16(a, b, acc[ct], 0, 0, 0);
        }
    }
    #pragma unroll
    for (int ct = 0; ct < 8; ct++) {
        float bcol = bias[ct * 16 + l16];
        #pragma unroll
        for (int r = 0; r < 4; r++) {
            int row = rbase + quad * 4 + r;
            if (row < M) {
                float v = acc[ct][r] + bcol;
                if (do_tanh) v = tanhf(v);
                outb[(size_t)row * 128 + ct * 16 + l16] = f2bf_u(v);
            }
        }
    }
}

// ---------------- prep: Wpk3 + bsum + W1b/W2b + tobf16 + buffer zeroing -------------

#define PR0 (1024 * 384)
#define PR1 (PR0 + 1024)
#define PR2 (PR1 + 16384)
#define PR3 (PR2 + 16384)
#define PR4 (PR3 + N_NODES * EMB / 4)
#define PR5 (PR4 + 2 * NSENT * 64)
#define PR6 (PR5 + NGRP * 32)
#define PR7 (PR6 + N_NODES)

__global__ void k_prep(const float* __restrict__ Wi, const float* __restrict__ Wh,
                       const float* __restrict__ bi, const float* __restrict__ bh,
                       const float* __restrict__ W1, const float* __restrict__ W2,
                       const float* __restrict__ inputs,
                       unsigned short* __restrict__ Wpk3, float* __restrict__ bsum,
                       unsigned short* __restrict__ W1b, unsigned short* __restrict__ W2b,
                       unsigned short* __restrict__ in_bf,
                       unsigned long long* __restrict__ hX,
                       int* __restrict__ gcnt, int* __restrict__ cnt) {
    int idx = blockIdx.x * 256 + threadIdx.x;
    if (idx < PR0) {
        int R = idx / 384, k = idx - R * 384;
        float v = (k < 128) ? Wi[R * 128 + k] : Wh[R * 256 + (k - 128)];
        int g = R >> 8, u = R & 255;
        int usl = u >> 5, up = u & 31;
        int ct = g * 2 + (up >> 4);
        int l16v = up & 15;
        int ks = k >> 5, kk = k & 31;
        int quad = kk >> 3, jj = kk & 7;
        int lane = quad * 16 + l16v;
        Wpk3[(((size_t)usl * 12 + ks) * 8 + ct) * 512 + lane * 8 + jj] = f2bf_u(v);
    } else if (idx < PR1) {
        int r = idx - PR0;
        bsum[r] = bi[r] + bh[r];
    } else if (idx < PR2) {
        int r = idx - PR1;
        W1b[r] = f2bf_u(W1[r]);
    } else if (idx < PR3) {
        int r = idx - PR2;
        W2b[r] = f2bf_u(W2[r]);
    } else if (idx < PR4) {
        int i = idx - PR3;
        float4 v = ((const float4*)inputs)[i];
        ushort4 u4;
        u4.x = f2bf_u(v.x); u4.y = f2bf_u(v.y); u4.z = f2bf_u(v.z); u4.w = f2bf_u(v.w);
        ((ushort4*)in_bf)[i] = u4;
    } else if (idx < PR5) {
        hX[idx - PR4] = 0ull;
    } else if (idx < PR6) {
        gcnt[idx - PR5] = 0;
    } else if (idx < PR7) {
        cnt[idx - PR6] = 0;
    }
}

// ---------------- LSTM: weight-stationary, wide device-coherent exchange -------------
// R26: R12's hv-under-xb reorder was null; sync DETECTION is settled (R9 skeleton).
// Remaining residual theory: the exchange DATA path -- 4096 8B atomic loads + 512 8B
// atomic stores per block-step. Device-scope atomic ops are exempt from wave
// coalescing; if serviced per-lane at the coherence point they alone explain the
// ~8K cyc/step residual. Change: hv -> 4x 16B global_load_dwordx4 sc0 sc1 (device-
// coherent, wave-coalescable: 4KB contiguous per wave); h store -> plain
// global_store_dwordx2 sc0 sc1. Ordering unchanged and R9-proven: producer {stores ->
// vmcnt(0) ACK -> relaxed atomic flag add}; consumer {flag observe -> barrier ->
// loads}. Asm loads need manual WAITVM0 + sched_barrier(0) before use (compiler
// doesn't track asm vmcnt). Values bit-identical.

__global__ void __launch_bounds__(512)
__attribute__((amdgpu_waves_per_eu(2, 2)))
k_lstm_ws8(const unsigned short* __restrict__ hn_bf,   // [N_NODES][128] bf16
           const unsigned short* __restrict__ Wpk3,    // packed, see k_prep
           const float* __restrict__ bsum,             // [1024]
           const int* __restrict__ sidx,               // [NSENT][MAXLEN]
           const int* __restrict__ lengths,            // [NSENT]
           unsigned long long* __restrict__ hX,        // [2][NSENT][64] (256 bf16/row)
           int* __restrict__ gcnt,                     // [NGRP*32] arrival ctrs (zeroed)
           float* __restrict__ h_last) {               // [NSENT][256] fp32
    __shared__ unsigned short xb[64 * 128];            // 16 KB x_t (chunk-swizzled)
    __shared__ unsigned short hb[64 * 256];            // 32 KB h_t (chunk-swizzled)
    __shared__ float gl[64 * 132];                     // 33 KB gates (independent region)
    __shared__ int nid_sh[NG * 33];                    // 8448 B

    int tid = threadIdx.x;
    int w = tid >> 6, lane = tid & 63;
    int l16 = lane & 15, quad = lane >> 4;
    int usl = blockIdx.x >> 5;        // u-slice 0..7
    int grp = blockIdx.x & 31;        // sentence group 0..31 (same-XCD under %8 rr)
    int s0 = grp * NG;
    const short* hnp = (const short*)hn_bf;

    int m2 = w >> 2, cp4 = w & 3;     // GEMM wave grid: 2 m-groups x 4 col-groups (32x32)
    int row0 = m2 * 32 + l16, row1 = row0 + 16;

    // ---- prologue: this wave's 24 B-fragments -> REGISTERS (time-invariant) ----
    short8 breg[12][2];
    {
        const short* wsrc = (const short*)Wpk3 + (size_t)usl * 49152 + lane * 8;
        #pragma unroll
        for (int ks = 0; ks < 12; ks++)
            #pragma unroll
            for (int c = 0; c < 2; c++)
                breg[ks][c] = *(const short8*)(wsrc + (size_t)(ks * 8 + cp4 * 2 + c) * 512);
    }
    // bias for this wave's two 16-col tiles (folded into acc init each step)
    float bc0 = bsum[cp4 * 256 + usl * 32 + l16];
    float bc1 = bsum[cp4 * 256 + usl * 32 + 16 + l16];

    // x0 -> xb via async gload (pre-swizzled source)
    #pragma unroll
    for (int i = 0; i < 2; i++) {
        int row = w * 8 + i * 4 + quad;
        int nid = sidx[(size_t)(s0 + row) * MAXLEN + 0];
        int schunk = (l16 & ~7) | ((l16 ^ row) & 7);
        gload_lds16(hnp + (size_t)nid * 128 + schunk * 8,
                    (void*)((char*)xb + (size_t)(w * 8 + i * 4) * 256));
    }
    for (int i = tid; i < NG * 32; i += 512)
        nid_sh[(i >> 5) * 33 + (i & 31)] = sidx[(size_t)(s0 + (i >> 5)) * MAXLEN + (i & 31)];
    for (int i = tid; i < 64 * 128; i += 512) ((unsigned int*)hb)[i] = 0;  // h_{-1}=0

    // pointwise-thread constants: (psent = tid>>3, 4 h-cols u'0 = (tid&7)*4 ..)
    int psent = tid >> 3, j8 = tid & 7, u0 = j8 * 4;
    int len_reg = lengths[s0 + psent];
    float c_reg[4] = {};

    short8 xr[2];                     // x(t+1) register prefetch

    __syncthreads();                  // prologue staged (drains gload vmcnt)

    #pragma unroll 1
    for (int t = 0; t < MAXLEN; t++) {
        // ---- issue x(t+1) global->reg prefetch ----
        if (t + 1 < MAXLEN) {
            int row = tid >> 3;
            int nid = nid_sh[row * 33 + (t + 1)];
            #pragma unroll
            for (int k = 0; k < 2; k++) {
                int slot = j8 * 2 + k;
                int c = (slot & ~7) | ((slot ^ row) & 7);
                xr[k] = *(const short8*)(hnp + (size_t)nid * 128 + c * 8);
            }
        }

        // ---- x-part GEMM: ks 0..3 (xb only) -- runs BEFORE the spin ----
        f32x4 acc00 = {bc0, bc0, bc0, bc0};
        f32x4 acc01 = {bc1, bc1, bc1, bc1};
        f32x4 acc10 = {bc0, bc0, bc0, bc0};
        f32x4 acc11 = {bc1, bc1, bc1, bc1};
        #pragma unroll
        for (int ks = 0; ks < 4; ks++) {
            int kc = ks * 4 + quad;
            short8 a0 = *(const short8*)(xb + row0 * 128 + (((kc & ~7) | ((kc ^ row0) & 7)) * 8));
            short8 a1 = *(const short8*)(xb + row1 * 128 + (((kc & ~7) | ((kc ^ row1) & 7)) * 8));
            acc00 = __builtin_amdgcn_mfma_f32_16x16x32_bf16(a0, breg[ks][0], acc00, 0, 0, 0);
            acc01 = __builtin_amdgcn_mfma_f32_16x16x32_bf16(a0, breg[ks][1], acc01, 0, 0, 0);
            acc10 = __builtin_amdgcn_mfma_f32_16x16x32_bf16(a1, breg[ks][0], acc10, 0, 0, 0);
            acc11 = __builtin_amdgcn_mfma_f32_16x16x32_bf16(a1, breg[ks][1], acc11, 0, 0, 0);
        }

        // ---- spin (publish->observe hidden under x-part) ----
        if (t > 0 && tid == 0) {
            while (__hip_atomic_load(&gcnt[grp * 32], __ATOMIC_RELAXED,
                                     __HIP_MEMORY_SCOPE_AGENT) < 8 * t)
                __builtin_amdgcn_s_sleep(1);
        }
        __syncthreads();   // Bspin: broadcast; also proves all waves passed x-GEMM

        // ---- h_t: wide device-coherent loads (issued first, RT under xb writes) ----
        u32x4 h0, h1, h2, h3;
        if (t > 0) {
            const char* hr = (const char*)(hX + (size_t)(t & 1) * NSENT * 64
                                           + (size_t)(s0 + psent) * 64 + j8 * 8);
            h0 = dc_load16(hr);
            h1 = dc_load16(hr + 16);
            h2 = dc_load16(hr + 32);
            h3 = dc_load16(hr + 48);
        }

        // ---- xb(t+1) ds_writes (xr long-arrived) ----
        if (t + 1 < MAXLEN) {
            int row = tid >> 3;
            #pragma unroll
            for (int k = 0; k < 2; k++) {
                int slot = j8 * 2 + k;
                *(short8*)(xb + row * 128 + slot * 8) = xr[k];
            }
        }

        // ---- h_t -> hb (asm loads: manual drain + scheduling fence) ----
        if (t > 0) {
            WAITVM0();
#if __has_builtin(__builtin_amdgcn_sched_barrier)
            __builtin_amdgcn_sched_barrier(0);
#endif
            #pragma unroll
            for (int p = 0; p < 4; p++) {
                int cc = j8 * 4 + p;
                int slot = (cc & ~7) | ((cc ^ psent) & 7);
                u32x4 hv = (p == 0) ? h0 : (p == 1) ? h1 : (p == 2) ? h2 : h3;
                *(short8*)(hb + psent * 256 + slot * 8) = *(short8*)&hv;
            }
        }
        __syncthreads();   // Bh: xb(t+1)/hb(t) visible to all waves

        // ---- h-part GEMM: ks 4..11 (hb) ----
        #pragma unroll
        for (int ks = 4; ks < 12; ks++) {
            int kc = (ks - 4) * 4 + quad;
            short8 a0 = *(const short8*)(hb + row0 * 256 + (((kc & ~7) | ((kc ^ row0) & 7)) * 8));
            short8 a1 = *(const short8*)(hb + row1 * 256 + (((kc & ~7) | ((kc ^ row1) & 7)) * 8));
            acc00 = __builtin_amdgcn_mfma_f32_16x16x32_bf16(a0, breg[ks][0], acc00, 0, 0, 0);
            acc01 = __builtin_amdgcn_mfma_f32_16x16x32_bf16(a0, breg[ks][1], acc01, 0, 0, 0);
            acc10 = __builtin_amdgcn_mfma_f32_16x16x32_bf16(a1, breg[ks][0], acc10, 0, 0, 0);
            acc11 = __builtin_amdgcn_mfma_f32_16x16x32_bf16(a1, breg[ks][1], acc11, 0, 0, 0);
        }

        // ---- acc (pre-biased) -> gates f32 [64][132] (ncol = g*32+u', g = cp4) ----
        #pragma unroll
        for (int r = 0; r < 4; r++) {
            int se0 = m2 * 32 + quad * 4 + r;
            int se1 = se0 + 16;
            gl[se0 * 132 + cp4 * 32 + l16]      = acc00[r];
            gl[se0 * 132 + cp4 * 32 + 16 + l16] = acc01[r];
            gl[se1 * 132 + cp4 * 32 + l16]      = acc10[r];
            gl[se1 * 132 + cp4 * 32 + 16 + l16] = acc11[r];
        }
        __syncthreads();   // B3: gates ready

        // ---- pointwise c/h for (psent, u-cols usl*32+u0 .. +3) ----
        {
            float4 G[4];
            #pragma unroll
            for (int g = 0; g < 4; g++)
                G[g] = *(const float4*)&gl[psent * 132 + g * 32 + u0];
            float hv4[4];
            const float* Gp0 = (const float*)&G[0];
            const float* Gp1 = (const float*)&G[1];
            const float* Gp2 = (const float*)&G[2];
            const float* Gp3 = (const float*)&G[3];
            #pragma unroll
            for (int j = 0; j < 4; j++) {
                float i_ = fsig(Gp0[j]);
                float f_ = fsig(Gp1[j]);
                float g_ = ftanh(Gp2[j]);
                float o_ = fsig(Gp3[j]);
                float c = f_ * c_reg[j] + i_ * g_;
                c_reg[j] = c;
                hv4[j] = o_ * ftanh(c);
            }
            unsigned long long hq =
                  (unsigned long long)f2bf_u(hv4[0])
                | ((unsigned long long)f2bf_u(hv4[1]) << 16)
                | ((unsigned long long)f2bf_u(hv4[2]) << 32)
                | ((unsigned long long)f2bf_u(hv4[3]) << 48);
            unsigned long long* hw = hX + (size_t)((t + 1) & 1) * NSENT * 64
                                     + (size_t)(s0 + psent) * 64 + usl * 8 + j8;
            u32x2 sv;
            sv.x = (unsigned int)(hq & 0xffffffffull);
            sv.y = (unsigned int)(hq >> 32);
            dc_store8(hw, sv);
            if (len_reg == t + 1) {
                float4 o4 = make_float4(hv4[0], hv4[1], hv4[2], hv4[3]);
                *(float4*)&h_last[(size_t)(s0 + psent) * 256 + usl * 32 + u0] = o4;
            }
        }

        // ---- tail: ACK hX stores at coherence point, arrive ----
        if (t + 1 < MAXLEN) {
            WAITVM0();         // dc_store8 ACK'd at coherence point
            __syncthreads();   // Bx: joins all waves' ACKs
            if (tid == 0)
                __hip_atomic_fetch_add(&gcnt[grp * 32], 1, __ATOMIC_RELAXED,
                                       __HIP_MEMORY_SCOPE_AGENT);
        }
    }
}

// ---------------- classifier ----------------

__global__ void k_classifier(const float* __restrict__ h_last,
                             const float* __restrict__ Wc1, const float* __restrict__ bc1,
                             const float* __restrict__ Wc2, const float* __restrict__ bc2,
                             float* __restrict__ out) {
    int lane = threadIdx.x & 63;
    int wslot = threadIdx.x >> 6;
    int s = blockIdx.x * 4 + wslot;
    __shared__ float e_sh[4][256];
    const float* hr = h_last + (size_t)s * 256;
    #pragma unroll
    for (int i = 0; i < 4; i++) {
        float v = hr[lane + 64 * i];
        e_sh[wslot][lane + 64 * i] = fmaxf(v, 0.f);
    }
    __syncthreads();
    float zpart = 0.f;
    #pragma unroll
    for (int jj = 0; jj < 2; jj++) {
        int j = lane + 64 * jj;
        float a = bc1[j];
        const float4* wr = (const float4*)(Wc1 + (size_t)j * 256);
        #pragma unroll 8
        for (int k4 = 0; k4 < 64; k4++) {
            float4 wv = wr[k4];
            float4 e = *(const float4*)&e_sh[wslot][k4 * 4];
            a += wv.x * e.x + wv.y * e.y + wv.z * e.z + wv.w * e.w;
        }
        a = fmaxf(a, 0.f);
        zpart += a * Wc2[j];
    }
    #pragma unroll
    for (int off = 32; off > 0; off >>= 1) zpart += __shfl_down(zpart, off);
    if (lane == 0) out[s] = zpart + bc2[0];
}

// ---------------- launcher (12 dispatches, 0 memsets) ----------------

extern "C" void kernel_launch(void* const* d_in, const int* in_sizes, int n_in,
                              void* d_out, int out_size, void* d_ws, size_t ws_size,
                              hipStream_t stream) {
    const float* inputs = (const float*)d_in[0];
    const float* W1  = (const float*)d_in[1];
    const float* b1  = (const float*)d_in[2];
    const float* W2  = (const float*)d_in[3];
    const float* b2  = (const float*)d_in[4];
    const float* Wi  = (const float*)d_in[5];
    const float* Wh  = (const float*)d_in[6];
    const float* bi  = (const float*)d_in[7];
    const float* bh  = (const float*)d_in[8];
    const float* Wc1 = (const float*)d_in[9];
    const float* bc1 = (const float*)d_in[10];
    const float* Wc2 = (const float*)d_in[11];
    const float* bc2 = (const float*)d_in[12];
    const int* src      = (const int*)d_in[13];
    const int* dst      = (const int*)d_in[14];
    const int* sidx     = (const int*)d_in[15];
    const int* lengths  = (const int*)d_in[16];
    float* out = (float*)d_out;

    char* ws = (char*)d_ws;
    size_t off = 0;
    auto alloc = [&](size_t bytes) -> void* {
        void* p = ws + off;
        off = (off + bytes + 255) & ~(size_t)255;
        return p;
    };
    unsigned short* in_bf  = (unsigned short*)alloc(2 * (size_t)N_NODES * EMB);
    unsigned short* agg_bf = (unsigned short*)alloc(2 * (size_t)N_NODES * EMB);
    unsigned short* h_bf   = (unsigned short*)alloc(2 * (size_t)N_NODES * EMB);
    unsigned short* hn_bf  = (unsigned short*)alloc(2 * (size_t)N_NODES * EMB);
    int*   row_ptr  = (int*)alloc(sizeof(int) * (N_NODES + 1));
    int*   cnt      = (int*)alloc(sizeof(int) * N_NODES);
    int*   blk      = (int*)alloc(sizeof(int) * SCAN_NB);
    int*   edge_src = (int*)alloc(sizeof(int) * N_EDGES);
    unsigned short* Wpk3 = (unsigned short*)alloc(2 * 8 * 12 * 8 * 512);  // 768 KB
    unsigned short* W1b  = (unsigned short*)alloc(2 * 128 * 128);
    unsigned short* W2b  = (unsigned short*)alloc(2 * 128 * 128);
    float* bsum     = (float*)alloc(sizeof(float) * 1024);
    float* hlast    = (float*)alloc(sizeof(float) * NSENT * LH);
    unsigned long long* hX = (unsigned long long*)alloc(2 * (size_t)NSENT * 64 * 8);  // 2 MB
    int* gcnt       = (int*)alloc(sizeof(int) * NGRP * 32);

    // fused prep: weights pack + bf16 converts + all buffer zeroing
    k_prep<<<(PR7 + 255) / 256, 256, 0, stream>>>(
        Wi, Wh, bi, bh, W1, W2, inputs, Wpk3, bsum, W1b, W2b, in_bf, hX, gcnt, cnt);

    // CSR build (cnt zeroed by k_prep; re-zeroed for scatter inside k_scan_add)
    k_hist<<<(N_EDGES + 255) / 256, 256, 0, stream>>>(dst, cnt);
    k_scan_blk<<<SCAN_NB, 256, 0, stream>>>(cnt, row_ptr, blk);
    k_scan_tot<<<1, 256, 0, stream>>>(blk);
    k_scan_add<<<SCAN_NB, 256, 0, stream>>>(row_ptr, blk, cnt);
    k_scatter<<<(N_EDGES + 255) / 256, 256, 0, stream>>>(src, dst, row_ptr, cnt, edge_src);

    // GCN (bf16 path)
    k_aggregate_bf<<<(N_NODES * 64) / 256, 256, 0, stream>>>(in_bf, row_ptr, edge_src, agg_bf);
    k_gcn_mfma<<<(N_NODES + 63) / 64, 256, 0, stream>>>(agg_bf, W1b, b1, h_bf, N_NODES, 1);
    k_aggregate_bf<<<(N_NODES * 64) / 256, 256, 0, stream>>>(h_bf, row_ptr, edge_src, agg_bf);
    k_gcn_mfma<<<(N_NODES + 63) / 64, 256, 0, stream>>>(agg_bf, W2b, b2, hn_bf, N_NODES, 0);

    // LSTM: weight-stationary (B in VGPRs), wide device-coherent exchange
    k_lstm_ws8<<<NGRP * 8, 512, 0, stream>>>(hn_bf, Wpk3, bsum, sidx, lengths,
                                             hX, gcnt, hlast);

    // classifier
    k_classifier<<<NSENT / 4, 256, 0, stream>>>(hlast, Wc1, bc1, Wc2, bc2, out);
}